// Round 5
// baseline (757.029 us; speedup 1.0000x reference)
//
#include <hip/hip_runtime.h>
#include <hip/hip_bf16.h>

// ---------------------------------------------------------------------------
// we[k] = sum_c We[k][c] * att_edge[c]  (per layer, 32 values each)
// ---------------------------------------------------------------------------
__global__ void we_kernel(const float* __restrict__ We1, const float* __restrict__ ae1v,
                          const float* __restrict__ We2, const float* __restrict__ ae2v,
                          float* __restrict__ we1, float* __restrict__ we2) {
    int t = threadIdx.x;            // 64 threads
    const float* W = (t < 32) ? We1 : We2;
    const float* a = (t < 32) ? ae1v : ae2v;
    float* o       = (t < 32) ? we1 : we2;
    int k = t & 31;
    float s = 0.f;
    for (int c = 0; c < 64; ++c) s += W[k * 64 + c] * a[c];
    o[k] = s;
}

// ---------------------------------------------------------------------------
// in-degree count
// ---------------------------------------------------------------------------
__global__ __launch_bounds__(256)
void count_kernel(const int* __restrict__ eidx, int* __restrict__ cnt, int E) {
    int e = blockIdx.x * 256 + threadIdx.x;
    if (e < E) atomicAdd(&cnt[eidx[E + e]], 1);
}

// ---------------------------------------------------------------------------
// scan stage A: per-256-chunk sums
// ---------------------------------------------------------------------------
__global__ __launch_bounds__(256)
void scanA_kernel(const int* __restrict__ cnt, int* __restrict__ bsum, int n) {
    int idx = blockIdx.x * 256 + threadIdx.x;
    int v = (idx < n) ? cnt[idx] : 0;
#pragma unroll
    for (int off = 32; off >= 1; off >>= 1) v += __shfl_xor(v, off, 64);
    __shared__ int ws[4];
    int lane = threadIdx.x & 63, wid = threadIdx.x >> 6;
    if (lane == 0) ws[wid] = v;
    __syncthreads();
    if (threadIdx.x == 0) bsum[blockIdx.x] = ws[0] + ws[1] + ws[2] + ws[3];
}

// ---------------------------------------------------------------------------
// scan stage B: exclusive scan of chunk sums (single wave)
// ---------------------------------------------------------------------------
__global__ void scanB_kernel(const int* __restrict__ bsum, int* __restrict__ boff, int nb) {
    int lane = threadIdx.x;   // 64
    int carry = 0;
    for (int base = 0; base < nb; base += 64) {
        int idx = base + lane;
        int v = (idx < nb) ? bsum[idx] : 0;
        int s = v;
#pragma unroll
        for (int off = 1; off < 64; off <<= 1) {
            int t = __shfl_up(s, off, 64);
            if (lane >= off) s += t;
        }
        if (idx < nb) boff[idx] = carry + s - v;
        carry += __shfl(s, 63, 64);
    }
}

// ---------------------------------------------------------------------------
// scan stage C: in-chunk scan + chunk offset -> row_ptr, cursor, bucket cursor
// bucket = 64 consecutive dst nodes
// ---------------------------------------------------------------------------
__global__ __launch_bounds__(256)
void scanC_kernel(const int* __restrict__ cnt, const int* __restrict__ boff,
                  int* __restrict__ row_ptr, int* __restrict__ cursor,
                  int* __restrict__ bcursor, int n, int E) {
    __shared__ int ws[4];
    __shared__ int woff[4];
    int idx = blockIdx.x * 256 + threadIdx.x;
    int lane = threadIdx.x & 63, wid = threadIdx.x >> 6;
    int v = (idx < n) ? cnt[idx] : 0;
    int s = v;
#pragma unroll
    for (int off = 1; off < 64; off <<= 1) {
        int t = __shfl_up(s, off, 64);
        if (lane >= off) s += t;
    }
    if (lane == 63) ws[wid] = s;
    __syncthreads();
    if (threadIdx.x == 0) {
        int run = 0;
        for (int w = 0; w < 4; ++w) { int t = ws[w]; woff[w] = run; run += t; }
    }
    __syncthreads();
    if (idx < n) {
        int ex = boff[blockIdx.x] + woff[wid] + s - v;
        row_ptr[idx] = ex;
        cursor[idx] = ex;
        if ((idx & 63) == 0) bcursor[idx >> 6] = ex;
    }
    if (idx == 0) row_ptr[n] = E;
}

// ---------------------------------------------------------------------------
// phase 1: per-edge a_edge for both layers + append into dst-BUCKET window
// record = {ae1, ae2, src_bits, dst_bits}
// ---------------------------------------------------------------------------
__global__ __launch_bounds__(256)
void bucket_scatter_kernel(const float4* __restrict__ ea, const int* __restrict__ eidx,
                           const float* __restrict__ we1g, const float* __restrict__ we2g,
                           int* __restrict__ bcursor, float4* __restrict__ s_tmp, int E) {
    __shared__ float w1s[32], w2s[32];
    if (threadIdx.x < 32) w1s[threadIdx.x] = we1g[threadIdx.x];
    else if (threadIdx.x < 64) w2s[threadIdx.x - 32] = we2g[threadIdx.x - 32];
    __syncthreads();
    int e = blockIdx.x * 256 + threadIdx.x;
    if (e >= E) return;
    int src = eidx[e];
    int dst = eidx[E + e];
    float acc1 = 0.f, acc2 = 0.f;
#pragma unroll
    for (int q = 0; q < 8; ++q) {
        float4 v = ea[(size_t)e * 8 + q];
        acc1 += v.x * w1s[q * 4 + 0] + v.y * w1s[q * 4 + 1] +
                v.z * w1s[q * 4 + 2] + v.w * w1s[q * 4 + 3];
        acc2 += v.x * w2s[q * 4 + 0] + v.y * w2s[q * 4 + 1] +
                v.z * w2s[q * 4 + 2] + v.w * w2s[q * 4 + 3];
    }
    int pos = atomicAdd(&bcursor[dst >> 6], 1);
    s_tmp[pos] = make_float4(acc1, acc2, __int_as_float(src), __int_as_float(dst));
}

// ---------------------------------------------------------------------------
// phase 2: within-bucket exact placement (one workgroup per bucket)
// ---------------------------------------------------------------------------
__global__ __launch_bounds__(256)
void sort_kernel(const int* __restrict__ row_ptr, const float4* __restrict__ s_tmp,
                 int* __restrict__ cursor, float4* __restrict__ s_rec, int n) {
    int node0 = blockIdx.x << 6;
    int node1 = node0 + 64; if (node1 > n) node1 = n;
    int start = row_ptr[node0], end = row_ptr[node1];
    for (int j = start + threadIdx.x; j < end; j += 256) {
        float4 r = s_tmp[j];
        int dst = __float_as_int(r.w);
        int pos = atomicAdd(&cursor[dst], 1);
        s_rec[pos] = r;
    }
}

// ---------------------------------------------------------------------------
// H = X @ W (one wave per node, lane = out channel) + attn logit dots
// ---------------------------------------------------------------------------
template <int INC>
__global__ __launch_bounds__(256)
void gemm_kernel(const float* __restrict__ X, const float* __restrict__ W,
                 const float* __restrict__ asv, const float* __restrict__ adv,
                 float* __restrict__ H, float* __restrict__ a_src,
                 float* __restrict__ a_dst, int n) {
    __shared__ float Wl[INC * 64];
    for (int t = threadIdx.x; t < INC * 64; t += 256) Wl[t] = W[t];
    __syncthreads();
    int wid = threadIdx.x >> 6, lane = threadIdx.x & 63;
    int i = blockIdx.x * 4 + wid;
    if (i >= n) return;
    const float4* xr = (const float4*)(X + (size_t)i * INC);
    float acc = 0.f;
#pragma unroll
    for (int k4 = 0; k4 < INC / 4; ++k4) {
        float4 xv = xr[k4];
        acc += xv.x * Wl[(k4 * 4 + 0) * 64 + lane];
        acc += xv.y * Wl[(k4 * 4 + 1) * 64 + lane];
        acc += xv.z * Wl[(k4 * 4 + 2) * 64 + lane];
        acc += xv.w * Wl[(k4 * 4 + 3) * 64 + lane];
    }
    H[(size_t)i * 64 + lane] = acc;
    float s = acc * asv[lane];
    float d = acc * adv[lane];
#pragma unroll
    for (int off = 32; off >= 1; off >>= 1) {
        s += __shfl_xor(s, off, 64);
        d += __shfl_xor(d, off, 64);
    }
    if (lane == 0) { a_src[i] = s; a_dst[i] = d; }
}

// ---------------------------------------------------------------------------
// fused aggregation: softmax weights in registers (lane = edge), then
// gather phase as wave = 4 edge-slots x 16 channel-quads (float4 loads)
// ---------------------------------------------------------------------------
template <int AEIDX, bool RELU>
__global__ __launch_bounds__(256)
void agg_fused_kernel(const int* __restrict__ row_ptr, const float4* __restrict__ s_rec,
                      const float* __restrict__ a_srcv, const float* __restrict__ a_dstv,
                      const float4* __restrict__ H4, const float* __restrict__ bias,
                      float* __restrict__ out, int n) {
    int wid = threadIdx.x >> 6, lane = threadIdx.x & 63;
    int i = blockIdx.x * 4 + wid;
    if (i >= n) return;
    int start = row_ptr[i], end = row_ptr[i + 1];
    int deg = end - start;
    float adst = a_dstv[i];

    // ---- phase 1: logits (lane = edge), deg<=128 fast path in regs ----
    float al0 = -INFINITY, al1 = -INFINITY;
    int src0 = 0, src1 = 0;
    float aeloc = 0.f;
    {
        int j = start + lane;
        if (j < end) {
            float4 r = s_rec[j];
            float ae = (AEIDX == 0) ? r.x : r.y;
            src0 = __float_as_int(r.z);
            float a = a_srcv[src0] + adst + ae;
            al0 = a > 0.f ? a : 0.2f * a;
            aeloc += ae;
        }
    }
    if (deg > 64) {
        int j = start + 64 + lane;
        if (j < end) {
            float4 r = s_rec[j];
            float ae = (AEIDX == 0) ? r.x : r.y;
            src1 = __float_as_int(r.z);
            float a = a_srcv[src1] + adst + ae;
            al1 = a > 0.f ? a : 0.2f * a;
            aeloc += ae;
        }
    }
    float mloc = fmaxf(al0, al1);
    for (int base = start + 128; base < end; base += 64) {   // rare spill
        int j = base + lane;
        if (j < end) {
            float4 r = s_rec[j];
            float ae = (AEIDX == 0) ? r.x : r.y;
            int s = __float_as_int(r.z);
            float a = a_srcv[s] + adst + ae;
            a = a > 0.f ? a : 0.2f * a;
            mloc = fmaxf(mloc, a);
            aeloc += ae;
        }
    }
#pragma unroll
    for (int off = 32; off >= 1; off >>= 1) {
        mloc = fmaxf(mloc, __shfl_xor(mloc, off, 64));
        aeloc += __shfl_xor(aeloc, off, 64);
    }
    float ael = aeloc / (float)(deg > 0 ? deg : 1);
    float als = a_srcv[i] + adst + ael;
    als = als > 0.f ? als : 0.2f * als;
    float m = fmaxf(mloc, als);

    float w0 = (start + lane < end)      ? __expf(al0 - m) : 0.f;
    float w1 = (start + 64 + lane < end) ? __expf(al1 - m) : 0.f;
    float dloc = w0 + w1;
    for (int base = start + 128; base < end; base += 64) {   // rare spill
        int j = base + lane;
        if (j < end) {
            float4 r = s_rec[j];
            float ae = (AEIDX == 0) ? r.x : r.y;
            int s = __float_as_int(r.z);
            float a = a_srcv[s] + adst + ae;
            a = a > 0.f ? a : 0.2f * a;
            dloc += __expf(a - m);
        }
    }
#pragma unroll
    for (int off = 32; off >= 1; off >>= 1) dloc += __shfl_xor(dloc, off, 64);
    float wself = __expf(als - m);
    float inv = 1.f / (dloc + wself + 1e-16f);

    // ---- phase 2: gather. wave = 4 edge-slots x 16 channel-quads ----
    int sub = lane >> 4;          // edge slot 0..3
    int c4  = lane & 15;          // channel quad
    float4 acc = make_float4(0.f, 0.f, 0.f, 0.f);
    int mainCnt = deg < 128 ? deg : 128;
    for (int r = 0; r < mainCnt; r += 4) {
        int rel = r + sub;                 // 0..127 (may overrun tail: w==0 there)
        float wa = __shfl(w0, rel & 63, 64);
        float wb = __shfl(w1, rel & 63, 64);
        int   sa = __shfl(src0, rel & 63, 64);
        int   sb = __shfl(src1, rel & 63, 64);
        float w = (rel < 64) ? wa : wb;
        int   s = (rel < 64) ? sa : sb;
        float4 hv = H4[(size_t)s * 16 + c4];
        acc.x += w * hv.x; acc.y += w * hv.y;
        acc.z += w * hv.z; acc.w += w * hv.w;
    }
    for (int j = start + 128; j < end; j += 4) {   // rare spill: recompute w
        int jj = j + sub;
        if (jj < end) {
            float4 r = s_rec[jj];
            float ae = (AEIDX == 0) ? r.x : r.y;
            int s = __float_as_int(r.z);
            float a = a_srcv[s] + adst + ae;
            a = a > 0.f ? a : 0.2f * a;
            float w = __expf(a - m);
            float4 hv = H4[(size_t)s * 16 + c4];
            acc.x += w * hv.x; acc.y += w * hv.y;
            acc.z += w * hv.z; acc.w += w * hv.w;
        }
    }
    // reduce across the 4 edge-slots (lanes differing in bits 4,5)
#pragma unroll
    for (int off = 16; off <= 32; off <<= 1) {
        acc.x += __shfl_xor(acc.x, off, 64);
        acc.y += __shfl_xor(acc.y, off, 64);
        acc.z += __shfl_xor(acc.z, off, 64);
        acc.w += __shfl_xor(acc.w, off, 64);
    }
    // self-loop + epilogue (all lanes consistent)
    float4 hv = H4[(size_t)i * 16 + c4];
    float4 bv = ((const float4*)bias)[c4];
    float4 o;
    o.x = (acc.x + wself * hv.x) * inv + bv.x;
    o.y = (acc.y + wself * hv.y) * inv + bv.y;
    o.z = (acc.z + wself * hv.z) * inv + bv.z;
    o.w = (acc.w + wself * hv.w) * inv + bv.w;
    if (RELU) {
        o.x = fmaxf(o.x, 0.f); o.y = fmaxf(o.y, 0.f);
        o.z = fmaxf(o.z, 0.f); o.w = fmaxf(o.w, 0.f);
    }
    if (sub == 0) ((float4*)out)[(size_t)i * 16 + c4] = o;
}

// ---------------------------------------------------------------------------
extern "C" void kernel_launch(void* const* d_in, const int* in_sizes, int n_in,
                              void* d_out, int out_size, void* d_ws, size_t ws_size,
                              hipStream_t stream) {
    const float* x        = (const float*)d_in[0];
    const int*   eidx     = (const int*)d_in[1];
    const float* eattr    = (const float*)d_in[2];
    const float* W1       = (const float*)d_in[3];
    const float* We1      = (const float*)d_in[4];
    const float* att_src1 = (const float*)d_in[5];
    const float* att_dst1 = (const float*)d_in[6];
    const float* att_edge1= (const float*)d_in[7];
    const float* b1       = (const float*)d_in[8];
    const float* W2       = (const float*)d_in[9];
    const float* We2      = (const float*)d_in[10];
    const float* att_src2 = (const float*)d_in[11];
    const float* att_dst2 = (const float*)d_in[12];
    const float* att_edge2= (const float*)d_in[13];
    const float* b2       = (const float*)d_in[14];
    float* out = (float*)d_out;

    const int n = in_sizes[0] / 128;    // 50000
    const int E = in_sizes[1] / 2;      // 1600000

    char* ws = (char*)d_ws;
    size_t off = 0;
    auto carve = [&](size_t bytes) {
        char* p = ws + off;
        off = (off + bytes + 255) & ~(size_t)255;
        return p;
    };
    const int nblkScan = (n + 255) / 256;
    const int nbuckets = (n + 63) / 64;
    float*  we1    = (float*)carve(32 * 4);
    float*  we2    = (float*)carve(32 * 4);
    int*    cnt    = (int*)carve((size_t)n * 4);
    int*    bsum   = (int*)carve((size_t)nblkScan * 4);
    int*    boff   = (int*)carve((size_t)nblkScan * 4);
    int*    row_ptr= (int*)carve((size_t)(n + 1) * 4);
    int*    cursor = (int*)carve((size_t)n * 4);
    int*    bcursor= (int*)carve((size_t)nbuckets * 4);
    float4* s_tmp  = (float4*)carve((size_t)E * 16);
    float4* s_rec  = (float4*)carve((size_t)E * 16);
    float*  bufA   = (float*)carve((size_t)n * 64 * 4);  // H (both layers)
    float*  bufB   = (float*)carve((size_t)n * 64 * 4);  // relu(gat1 out)
    float*  a_src  = (float*)carve((size_t)n * 4);
    float*  a_dst  = (float*)carve((size_t)n * 4);

    hipMemsetAsync(cnt, 0, (size_t)n * 4, stream);

    we_kernel<<<1, 64, 0, stream>>>(We1, att_edge1, We2, att_edge2, we1, we2);

    int egrid = (E + 255) / 256;
    count_kernel<<<egrid, 256, 0, stream>>>(eidx, cnt, E);
    scanA_kernel<<<nblkScan, 256, 0, stream>>>(cnt, bsum, n);
    scanB_kernel<<<1, 64, 0, stream>>>(bsum, boff, nblkScan);
    scanC_kernel<<<nblkScan, 256, 0, stream>>>(cnt, boff, row_ptr, cursor,
                                               bcursor, n, E);

    bucket_scatter_kernel<<<egrid, 256, 0, stream>>>((const float4*)eattr, eidx,
                                                     we1, we2, bcursor, s_tmp, E);
    sort_kernel<<<nbuckets, 256, 0, stream>>>(row_ptr, s_tmp, cursor, s_rec, n);

    int ngrid = (n + 3) / 4;
    // layer 1
    gemm_kernel<128><<<ngrid, 256, 0, stream>>>(x, W1, att_src1, att_dst1,
                                                bufA, a_src, a_dst, n);
    agg_fused_kernel<0, true><<<ngrid, 256, 0, stream>>>(row_ptr, s_rec, a_src,
                                                         a_dst, (const float4*)bufA,
                                                         b1, bufB, n);
    // layer 2
    gemm_kernel<64><<<ngrid, 256, 0, stream>>>(bufB, W2, att_src2, att_dst2,
                                               bufA, a_src, a_dst, n);
    agg_fused_kernel<1, false><<<ngrid, 256, 0, stream>>>(row_ptr, s_rec, a_src,
                                                          a_dst, (const float4*)bufA,
                                                          b2, out, n);
}

// Round 6
// 428.729 us; speedup vs baseline: 1.7658x; 1.7658x over previous
//
#include <hip/hip_runtime.h>
#include <hip/hip_bf16.h>

// ---------------------------------------------------------------------------
// zero cnt (hipMemsetAsync's fill kernel costs 119us/replay for 200KB!)
// ---------------------------------------------------------------------------
__global__ __launch_bounds__(256)
void zero_kernel(int* __restrict__ p, int n) {
    int i = blockIdx.x * 256 + threadIdx.x;
    if (i < n) p[i] = 0;
}

// ---------------------------------------------------------------------------
// we[k] = sum_c We[k][c] * att_edge[c]  (per layer, 32 values each)
// ---------------------------------------------------------------------------
__global__ void we_kernel(const float* __restrict__ We1, const float* __restrict__ ae1v,
                          const float* __restrict__ We2, const float* __restrict__ ae2v,
                          float* __restrict__ we1, float* __restrict__ we2) {
    int t = threadIdx.x;            // 64 threads
    const float* W = (t < 32) ? We1 : We2;
    const float* a = (t < 32) ? ae1v : ae2v;
    float* o       = (t < 32) ? we1 : we2;
    int k = t & 31;
    float s = 0.f;
    for (int c = 0; c < 64; ++c) s += W[k * 64 + c] * a[c];
    o[k] = s;
}

// ---------------------------------------------------------------------------
// in-degree count + per-edge rank within its dst segment
// ---------------------------------------------------------------------------
__global__ __launch_bounds__(256)
void count_kernel(const int* __restrict__ eidx, int* __restrict__ cnt,
                  int* __restrict__ rank, int E) {
    int e = blockIdx.x * 256 + threadIdx.x;
    if (e < E) rank[e] = atomicAdd(&cnt[eidx[E + e]], 1);
}

// ---------------------------------------------------------------------------
// scan stage A: per-256-chunk sums
// ---------------------------------------------------------------------------
__global__ __launch_bounds__(256)
void scanA_kernel(const int* __restrict__ cnt, int* __restrict__ bsum, int n) {
    int idx = blockIdx.x * 256 + threadIdx.x;
    int v = (idx < n) ? cnt[idx] : 0;
#pragma unroll
    for (int off = 32; off >= 1; off >>= 1) v += __shfl_xor(v, off, 64);
    __shared__ int ws[4];
    int lane = threadIdx.x & 63, wid = threadIdx.x >> 6;
    if (lane == 0) ws[wid] = v;
    __syncthreads();
    if (threadIdx.x == 0) bsum[blockIdx.x] = ws[0] + ws[1] + ws[2] + ws[3];
}

// ---------------------------------------------------------------------------
// scan stage B: exclusive scan of chunk sums (single wave)
// ---------------------------------------------------------------------------
__global__ void scanB_kernel(const int* __restrict__ bsum, int* __restrict__ boff, int nb) {
    int lane = threadIdx.x;   // 64
    int carry = 0;
    for (int base = 0; base < nb; base += 64) {
        int idx = base + lane;
        int v = (idx < nb) ? bsum[idx] : 0;
        int s = v;
#pragma unroll
        for (int off = 1; off < 64; off <<= 1) {
            int t = __shfl_up(s, off, 64);
            if (lane >= off) s += t;
        }
        if (idx < nb) boff[idx] = carry + s - v;
        carry += __shfl(s, 63, 64);
    }
}

// ---------------------------------------------------------------------------
// scan stage C: in-chunk scan + chunk offset -> row_ptr
// ---------------------------------------------------------------------------
__global__ __launch_bounds__(256)
void scanC_kernel(const int* __restrict__ cnt, const int* __restrict__ boff,
                  int* __restrict__ row_ptr, int n, int E) {
    __shared__ int ws[4];
    __shared__ int woff[4];
    int idx = blockIdx.x * 256 + threadIdx.x;
    int lane = threadIdx.x & 63, wid = threadIdx.x >> 6;
    int v = (idx < n) ? cnt[idx] : 0;
    int s = v;
#pragma unroll
    for (int off = 1; off < 64; off <<= 1) {
        int t = __shfl_up(s, off, 64);
        if (lane >= off) s += t;
    }
    if (lane == 63) ws[wid] = s;
    __syncthreads();
    if (threadIdx.x == 0) {
        int run = 0;
        for (int w = 0; w < 4; ++w) { int t = ws[w]; woff[w] = run; run += t; }
    }
    __syncthreads();
    if (idx < n) row_ptr[idx] = boff[blockIdx.x] + woff[wid] + s - v;
    if (idx == 0) row_ptr[n] = E;
}

// ---------------------------------------------------------------------------
// per-edge a_edge for both layers + ATOMIC-FREE exact scatter into CSR:
// pos = row_ptr[dst] + rank[e].  record = {ae1, ae2, src_bits, 0}
// ---------------------------------------------------------------------------
__global__ __launch_bounds__(256)
void edge_scatter_kernel(const float4* __restrict__ ea, const int* __restrict__ eidx,
                         const int* __restrict__ rank, const int* __restrict__ row_ptr,
                         const float* __restrict__ we1g, const float* __restrict__ we2g,
                         float4* __restrict__ s_rec, int E) {
    __shared__ float w1s[32], w2s[32];
    if (threadIdx.x < 32) w1s[threadIdx.x] = we1g[threadIdx.x];
    else if (threadIdx.x < 64) w2s[threadIdx.x - 32] = we2g[threadIdx.x - 32];
    __syncthreads();
    int e = blockIdx.x * 256 + threadIdx.x;
    if (e >= E) return;
    int src = eidx[e];
    int dst = eidx[E + e];
    int rk  = rank[e];
    float acc1 = 0.f, acc2 = 0.f;
#pragma unroll
    for (int q = 0; q < 8; ++q) {
        float4 v = ea[(size_t)e * 8 + q];
        acc1 += v.x * w1s[q * 4 + 0] + v.y * w1s[q * 4 + 1] +
                v.z * w1s[q * 4 + 2] + v.w * w1s[q * 4 + 3];
        acc2 += v.x * w2s[q * 4 + 0] + v.y * w2s[q * 4 + 1] +
                v.z * w2s[q * 4 + 2] + v.w * w2s[q * 4 + 3];
    }
    int pos = row_ptr[dst] + rk;
    s_rec[pos] = make_float4(acc1, acc2, __int_as_float(src), 0.f);
}

// ---------------------------------------------------------------------------
// H = X @ W (one wave per node, lane = out channel) + attn logit dots
// ---------------------------------------------------------------------------
template <int INC>
__global__ __launch_bounds__(256)
void gemm_kernel(const float* __restrict__ X, const float* __restrict__ W,
                 const float* __restrict__ asv, const float* __restrict__ adv,
                 float* __restrict__ H, float* __restrict__ a_src,
                 float* __restrict__ a_dst, int n) {
    __shared__ float Wl[INC * 64];
    for (int t = threadIdx.x; t < INC * 64; t += 256) Wl[t] = W[t];
    __syncthreads();
    int wid = threadIdx.x >> 6, lane = threadIdx.x & 63;
    int i = blockIdx.x * 4 + wid;
    if (i >= n) return;
    const float4* xr = (const float4*)(X + (size_t)i * INC);
    float acc = 0.f;
#pragma unroll
    for (int k4 = 0; k4 < INC / 4; ++k4) {
        float4 xv = xr[k4];
        acc += xv.x * Wl[(k4 * 4 + 0) * 64 + lane];
        acc += xv.y * Wl[(k4 * 4 + 1) * 64 + lane];
        acc += xv.z * Wl[(k4 * 4 + 2) * 64 + lane];
        acc += xv.w * Wl[(k4 * 4 + 3) * 64 + lane];
    }
    H[(size_t)i * 64 + lane] = acc;
    float s = acc * asv[lane];
    float d = acc * adv[lane];
#pragma unroll
    for (int off = 32; off >= 1; off >>= 1) {
        s += __shfl_xor(s, off, 64);
        d += __shfl_xor(d, off, 64);
    }
    if (lane == 0) { a_src[i] = s; a_dst[i] = d; }
}

// ---------------------------------------------------------------------------
// fused aggregation: softmax weights in registers (lane = edge), then
// gather phase as wave = 4 edge-slots x 16 channel-quads (float4 loads)
// ---------------------------------------------------------------------------
template <int AEIDX, bool RELU>
__global__ __launch_bounds__(256)
void agg_fused_kernel(const int* __restrict__ row_ptr, const float4* __restrict__ s_rec,
                      const float* __restrict__ a_srcv, const float* __restrict__ a_dstv,
                      const float4* __restrict__ H4, const float* __restrict__ bias,
                      float* __restrict__ out, int n) {
    int wid = threadIdx.x >> 6, lane = threadIdx.x & 63;
    int i = blockIdx.x * 4 + wid;
    if (i >= n) return;
    int start = row_ptr[i], end = row_ptr[i + 1];
    int deg = end - start;
    float adst = a_dstv[i];

    // ---- phase 1: logits (lane = edge), deg<=128 fast path in regs ----
    float al0 = -INFINITY, al1 = -INFINITY;
    int src0 = 0, src1 = 0;
    float aeloc = 0.f;
    {
        int j = start + lane;
        if (j < end) {
            float4 r = s_rec[j];
            float ae = (AEIDX == 0) ? r.x : r.y;
            src0 = __float_as_int(r.z);
            float a = a_srcv[src0] + adst + ae;
            al0 = a > 0.f ? a : 0.2f * a;
            aeloc += ae;
        }
    }
    if (deg > 64) {
        int j = start + 64 + lane;
        if (j < end) {
            float4 r = s_rec[j];
            float ae = (AEIDX == 0) ? r.x : r.y;
            src1 = __float_as_int(r.z);
            float a = a_srcv[src1] + adst + ae;
            al1 = a > 0.f ? a : 0.2f * a;
            aeloc += ae;
        }
    }
    float mloc = fmaxf(al0, al1);
    for (int base = start + 128; base < end; base += 64) {   // rare spill
        int j = base + lane;
        if (j < end) {
            float4 r = s_rec[j];
            float ae = (AEIDX == 0) ? r.x : r.y;
            int s = __float_as_int(r.z);
            float a = a_srcv[s] + adst + ae;
            a = a > 0.f ? a : 0.2f * a;
            mloc = fmaxf(mloc, a);
            aeloc += ae;
        }
    }
#pragma unroll
    for (int off = 32; off >= 1; off >>= 1) {
        mloc = fmaxf(mloc, __shfl_xor(mloc, off, 64));
        aeloc += __shfl_xor(aeloc, off, 64);
    }
    float ael = aeloc / (float)(deg > 0 ? deg : 1);
    float als = a_srcv[i] + adst + ael;
    als = als > 0.f ? als : 0.2f * als;
    float m = fmaxf(mloc, als);

    float w0 = (start + lane < end)      ? __expf(al0 - m) : 0.f;
    float w1 = (start + 64 + lane < end) ? __expf(al1 - m) : 0.f;
    float dloc = w0 + w1;
    for (int base = start + 128; base < end; base += 64) {   // rare spill
        int j = base + lane;
        if (j < end) {
            float4 r = s_rec[j];
            float ae = (AEIDX == 0) ? r.x : r.y;
            int s = __float_as_int(r.z);
            float a = a_srcv[s] + adst + ae;
            a = a > 0.f ? a : 0.2f * a;
            dloc += __expf(a - m);
        }
    }
#pragma unroll
    for (int off = 32; off >= 1; off >>= 1) dloc += __shfl_xor(dloc, off, 64);
    float wself = __expf(als - m);
    float inv = 1.f / (dloc + wself + 1e-16f);

    // ---- phase 2: gather. wave = 4 edge-slots x 16 channel-quads ----
    int sub = lane >> 4;          // edge slot 0..3
    int c4  = lane & 15;          // channel quad
    float4 acc = make_float4(0.f, 0.f, 0.f, 0.f);
    int mainCnt = deg < 128 ? deg : 128;
    for (int r = 0; r < mainCnt; r += 4) {
        int rel = r + sub;                 // 0..127 (may overrun tail: w==0 there)
        float wa = __shfl(w0, rel & 63, 64);
        float wb = __shfl(w1, rel & 63, 64);
        int   sa = __shfl(src0, rel & 63, 64);
        int   sb = __shfl(src1, rel & 63, 64);
        float w = (rel < 64) ? wa : wb;
        int   s = (rel < 64) ? sa : sb;
        float4 hv = H4[(size_t)s * 16 + c4];
        acc.x += w * hv.x; acc.y += w * hv.y;
        acc.z += w * hv.z; acc.w += w * hv.w;
    }
    for (int j = start + 128; j < end; j += 4) {   // rare spill: recompute w
        int jj = j + sub;
        if (jj < end) {
            float4 r = s_rec[jj];
            float ae = (AEIDX == 0) ? r.x : r.y;
            int s = __float_as_int(r.z);
            float a = a_srcv[s] + adst + ae;
            a = a > 0.f ? a : 0.2f * a;
            float w = __expf(a - m);
            float4 hv = H4[(size_t)s * 16 + c4];
            acc.x += w * hv.x; acc.y += w * hv.y;
            acc.z += w * hv.z; acc.w += w * hv.w;
        }
    }
    // reduce across the 4 edge-slots (lanes differing in bits 4,5)
#pragma unroll
    for (int off = 16; off <= 32; off <<= 1) {
        acc.x += __shfl_xor(acc.x, off, 64);
        acc.y += __shfl_xor(acc.y, off, 64);
        acc.z += __shfl_xor(acc.z, off, 64);
        acc.w += __shfl_xor(acc.w, off, 64);
    }
    // self-loop + epilogue (all lanes consistent)
    float4 hv = H4[(size_t)i * 16 + c4];
    float4 bv = ((const float4*)bias)[c4];
    float4 o;
    o.x = (acc.x + wself * hv.x) * inv + bv.x;
    o.y = (acc.y + wself * hv.y) * inv + bv.y;
    o.z = (acc.z + wself * hv.z) * inv + bv.z;
    o.w = (acc.w + wself * hv.w) * inv + bv.w;
    if (RELU) {
        o.x = fmaxf(o.x, 0.f); o.y = fmaxf(o.y, 0.f);
        o.z = fmaxf(o.z, 0.f); o.w = fmaxf(o.w, 0.f);
    }
    if (sub == 0) ((float4*)out)[(size_t)i * 16 + c4] = o;
}

// ---------------------------------------------------------------------------
extern "C" void kernel_launch(void* const* d_in, const int* in_sizes, int n_in,
                              void* d_out, int out_size, void* d_ws, size_t ws_size,
                              hipStream_t stream) {
    const float* x        = (const float*)d_in[0];
    const int*   eidx     = (const int*)d_in[1];
    const float* eattr    = (const float*)d_in[2];
    const float* W1       = (const float*)d_in[3];
    const float* We1      = (const float*)d_in[4];
    const float* att_src1 = (const float*)d_in[5];
    const float* att_dst1 = (const float*)d_in[6];
    const float* att_edge1= (const float*)d_in[7];
    const float* b1       = (const float*)d_in[8];
    const float* W2       = (const float*)d_in[9];
    const float* We2      = (const float*)d_in[10];
    const float* att_src2 = (const float*)d_in[11];
    const float* att_dst2 = (const float*)d_in[12];
    const float* att_edge2= (const float*)d_in[13];
    const float* b2       = (const float*)d_in[14];
    float* out = (float*)d_out;

    const int n = in_sizes[0] / 128;    // 50000
    const int E = in_sizes[1] / 2;      // 1600000

    char* ws = (char*)d_ws;
    size_t off = 0;
    auto carve = [&](size_t bytes) {
        char* p = ws + off;
        off = (off + bytes + 255) & ~(size_t)255;
        return p;
    };
    const int nblkScan = (n + 255) / 256;
    float*  we1    = (float*)carve(32 * 4);
    float*  we2    = (float*)carve(32 * 4);
    int*    cnt    = (int*)carve((size_t)n * 4);
    int*    bsum   = (int*)carve((size_t)nblkScan * 4);
    int*    boff   = (int*)carve((size_t)nblkScan * 4);
    int*    row_ptr= (int*)carve((size_t)(n + 1) * 4);
    int*    rank   = (int*)carve((size_t)E * 4);
    float4* s_rec  = (float4*)carve((size_t)E * 16);
    float*  bufA   = (float*)carve((size_t)n * 64 * 4);  // H (both layers)
    float*  bufB   = (float*)carve((size_t)n * 64 * 4);  // relu(gat1 out)
    float*  a_src  = (float*)carve((size_t)n * 4);
    float*  a_dst  = (float*)carve((size_t)n * 4);

    zero_kernel<<<nblkScan, 256, 0, stream>>>(cnt, n);

    we_kernel<<<1, 64, 0, stream>>>(We1, att_edge1, We2, att_edge2, we1, we2);

    int egrid = (E + 255) / 256;
    count_kernel<<<egrid, 256, 0, stream>>>(eidx, cnt, rank, E);
    scanA_kernel<<<nblkScan, 256, 0, stream>>>(cnt, bsum, n);
    scanB_kernel<<<1, 64, 0, stream>>>(bsum, boff, nblkScan);
    scanC_kernel<<<nblkScan, 256, 0, stream>>>(cnt, boff, row_ptr, n, E);

    edge_scatter_kernel<<<egrid, 256, 0, stream>>>((const float4*)eattr, eidx,
                                                   rank, row_ptr, we1, we2,
                                                   s_rec, E);

    int ngrid = (n + 3) / 4;
    // layer 1
    gemm_kernel<128><<<ngrid, 256, 0, stream>>>(x, W1, att_src1, att_dst1,
                                                bufA, a_src, a_dst, n);
    agg_fused_kernel<0, true><<<ngrid, 256, 0, stream>>>(row_ptr, s_rec, a_src,
                                                         a_dst, (const float4*)bufA,
                                                         b1, bufB, n);
    // layer 2
    gemm_kernel<64><<<ngrid, 256, 0, stream>>>(bufB, W2, att_src2, att_dst2,
                                               bufA, a_src, a_dst, n);
    agg_fused_kernel<1, false><<<ngrid, 256, 0, stream>>>(row_ptr, s_rec, a_src,
                                                          a_dst, (const float4*)bufA,
                                                          b2, out, n);
}

// Round 7
// 351.536 us; speedup vs baseline: 2.1535x; 1.2196x over previous
//
#include <hip/hip_runtime.h>
#include <hip/hip_bf16.h>

// ---------------------------------------------------------------------------
// zero cnt
// ---------------------------------------------------------------------------
__global__ __launch_bounds__(256)
void zero_kernel(int* __restrict__ p, int n) {
    int i = blockIdx.x * 256 + threadIdx.x;
    if (i < n) p[i] = 0;
}

// ---------------------------------------------------------------------------
// we[k] = sum_c We[k][c] * att_edge[c]  (per layer, 32 values each)
// ---------------------------------------------------------------------------
__global__ void we_kernel(const float* __restrict__ We1, const float* __restrict__ ae1v,
                          const float* __restrict__ We2, const float* __restrict__ ae2v,
                          float* __restrict__ we1, float* __restrict__ we2) {
    int t = threadIdx.x;            // 64 threads
    const float* W = (t < 32) ? We1 : We2;
    const float* a = (t < 32) ? ae1v : ae2v;
    float* o       = (t < 32) ? we1 : we2;
    int k = t & 31;
    float s = 0.f;
    for (int c = 0; c < 64; ++c) s += W[k * 64 + c] * a[c];
    o[k] = s;
}

// ---------------------------------------------------------------------------
// fused streaming pass: edge-attr dot (both layers) + in-degree rank.
// ALL reads/writes sequential. record = {ae1, ae2, src_bits, (rank<<16)|dst}
// ---------------------------------------------------------------------------
__global__ __launch_bounds__(256)
void edge_pass_kernel(const float4* __restrict__ ea, const int* __restrict__ eidx,
                      const float* __restrict__ we1g, const float* __restrict__ we2g,
                      int* __restrict__ cnt, float4* __restrict__ s_tmp, int E) {
    __shared__ float w1s[32], w2s[32];
    if (threadIdx.x < 32) w1s[threadIdx.x] = we1g[threadIdx.x];
    else if (threadIdx.x < 64) w2s[threadIdx.x - 32] = we2g[threadIdx.x - 32];
    __syncthreads();
    int e = blockIdx.x * 256 + threadIdx.x;
    if (e >= E) return;
    float acc1 = 0.f, acc2 = 0.f;
#pragma unroll
    for (int q = 0; q < 8; ++q) {
        float4 v = ea[(size_t)e * 8 + q];
        acc1 += v.x * w1s[q * 4 + 0] + v.y * w1s[q * 4 + 1] +
                v.z * w1s[q * 4 + 2] + v.w * w1s[q * 4 + 3];
        acc2 += v.x * w2s[q * 4 + 0] + v.y * w2s[q * 4 + 1] +
                v.z * w2s[q * 4 + 2] + v.w * w2s[q * 4 + 3];
    }
    int src = eidx[e];
    int dst = eidx[E + e];
    int rk = atomicAdd(&cnt[dst], 1);           // rank within dst segment
    unsigned packed = ((unsigned)rk << 16) | (unsigned)dst;
    s_tmp[e] = make_float4(acc1, acc2, __int_as_float(src),
                           __int_as_float((int)packed));
}

// ---------------------------------------------------------------------------
// scan stage A: per-256-chunk sums
// ---------------------------------------------------------------------------
__global__ __launch_bounds__(256)
void scanA_kernel(const int* __restrict__ cnt, int* __restrict__ bsum, int n) {
    int idx = blockIdx.x * 256 + threadIdx.x;
    int v = (idx < n) ? cnt[idx] : 0;
#pragma unroll
    for (int off = 32; off >= 1; off >>= 1) v += __shfl_xor(v, off, 64);
    __shared__ int ws[4];
    int lane = threadIdx.x & 63, wid = threadIdx.x >> 6;
    if (lane == 0) ws[wid] = v;
    __syncthreads();
    if (threadIdx.x == 0) bsum[blockIdx.x] = ws[0] + ws[1] + ws[2] + ws[3];
}

// ---------------------------------------------------------------------------
// scan stage B: exclusive scan of chunk sums (single wave)
// ---------------------------------------------------------------------------
__global__ void scanB_kernel(const int* __restrict__ bsum, int* __restrict__ boff, int nb) {
    int lane = threadIdx.x;   // 64
    int carry = 0;
    for (int base = 0; base < nb; base += 64) {
        int idx = base + lane;
        int v = (idx < nb) ? bsum[idx] : 0;
        int s = v;
#pragma unroll
        for (int off = 1; off < 64; off <<= 1) {
            int t = __shfl_up(s, off, 64);
            if (lane >= off) s += t;
        }
        if (idx < nb) boff[idx] = carry + s - v;
        carry += __shfl(s, 63, 64);
    }
}

// ---------------------------------------------------------------------------
// scan stage C: in-chunk scan + chunk offset -> row_ptr
// ---------------------------------------------------------------------------
__global__ __launch_bounds__(256)
void scanC_kernel(const int* __restrict__ cnt, const int* __restrict__ boff,
                  int* __restrict__ row_ptr, int n, int E) {
    __shared__ int ws[4];
    __shared__ int woff[4];
    int idx = blockIdx.x * 256 + threadIdx.x;
    int lane = threadIdx.x & 63, wid = threadIdx.x >> 6;
    int v = (idx < n) ? cnt[idx] : 0;
    int s = v;
#pragma unroll
    for (int off = 1; off < 64; off <<= 1) {
        int t = __shfl_up(s, off, 64);
        if (lane >= off) s += t;
    }
    if (lane == 63) ws[wid] = s;
    __syncthreads();
    if (threadIdx.x == 0) {
        int run = 0;
        for (int w = 0; w < 4; ++w) { int t = ws[w]; woff[w] = run; run += t; }
    }
    __syncthreads();
    if (idx < n) row_ptr[idx] = boff[blockIdx.x] + woff[wid] + s - v;
    if (idx == 0) row_ptr[n] = E;
}

// ---------------------------------------------------------------------------
// scatter pass: sequential record read, single scattered 16B store.
// pos = row_ptr[dst] + rank (atomic-free, deterministic given ranks)
// ---------------------------------------------------------------------------
__global__ __launch_bounds__(256)
void scatter_kernel(const float4* __restrict__ s_tmp, const int* __restrict__ row_ptr,
                    float4* __restrict__ s_rec, int E) {
    int e = blockIdx.x * 256 + threadIdx.x;
    if (e >= E) return;
    float4 r = s_tmp[e];
    unsigned packed = (unsigned)__float_as_int(r.w);
    int dst = (int)(packed & 0xFFFFu);
    int rk  = (int)(packed >> 16);
    int pos = row_ptr[dst] + rk;
    s_rec[pos] = make_float4(r.x, r.y, r.z, 0.f);
}

// ---------------------------------------------------------------------------
// H = X @ W (one wave per node, lane = out channel) + attn logit dots
// ---------------------------------------------------------------------------
template <int INC>
__global__ __launch_bounds__(256)
void gemm_kernel(const float* __restrict__ X, const float* __restrict__ W,
                 const float* __restrict__ asv, const float* __restrict__ adv,
                 float* __restrict__ H, float* __restrict__ a_src,
                 float* __restrict__ a_dst, int n) {
    __shared__ float Wl[INC * 64];
    for (int t = threadIdx.x; t < INC * 64; t += 256) Wl[t] = W[t];
    __syncthreads();
    int wid = threadIdx.x >> 6, lane = threadIdx.x & 63;
    int i = blockIdx.x * 4 + wid;
    if (i >= n) return;
    const float4* xr = (const float4*)(X + (size_t)i * INC);
    float acc = 0.f;
#pragma unroll
    for (int k4 = 0; k4 < INC / 4; ++k4) {
        float4 xv = xr[k4];
        acc += xv.x * Wl[(k4 * 4 + 0) * 64 + lane];
        acc += xv.y * Wl[(k4 * 4 + 1) * 64 + lane];
        acc += xv.z * Wl[(k4 * 4 + 2) * 64 + lane];
        acc += xv.w * Wl[(k4 * 4 + 3) * 64 + lane];
    }
    H[(size_t)i * 64 + lane] = acc;
    float s = acc * asv[lane];
    float d = acc * adv[lane];
#pragma unroll
    for (int off = 32; off >= 1; off >>= 1) {
        s += __shfl_xor(s, off, 64);
        d += __shfl_xor(d, off, 64);
    }
    if (lane == 0) { a_src[i] = s; a_dst[i] = d; }
}

// ---------------------------------------------------------------------------
// fused aggregation: softmax weights in registers (lane = edge), then
// gather phase as wave = 4 edge-slots x 16 channel-quads (float4 loads)
// ---------------------------------------------------------------------------
template <int AEIDX, bool RELU>
__global__ __launch_bounds__(256)
void agg_fused_kernel(const int* __restrict__ row_ptr, const float4* __restrict__ s_rec,
                      const float* __restrict__ a_srcv, const float* __restrict__ a_dstv,
                      const float4* __restrict__ H4, const float* __restrict__ bias,
                      float* __restrict__ out, int n) {
    int wid = threadIdx.x >> 6, lane = threadIdx.x & 63;
    int i = blockIdx.x * 4 + wid;
    if (i >= n) return;
    int start = row_ptr[i], end = row_ptr[i + 1];
    int deg = end - start;
    float adst = a_dstv[i];

    // ---- phase 1: logits (lane = edge), deg<=128 fast path in regs ----
    float al0 = -INFINITY, al1 = -INFINITY;
    int src0 = 0, src1 = 0;
    float aeloc = 0.f;
    {
        int j = start + lane;
        if (j < end) {
            float4 r = s_rec[j];
            float ae = (AEIDX == 0) ? r.x : r.y;
            src0 = __float_as_int(r.z);
            float a = a_srcv[src0] + adst + ae;
            al0 = a > 0.f ? a : 0.2f * a;
            aeloc += ae;
        }
    }
    if (deg > 64) {
        int j = start + 64 + lane;
        if (j < end) {
            float4 r = s_rec[j];
            float ae = (AEIDX == 0) ? r.x : r.y;
            src1 = __float_as_int(r.z);
            float a = a_srcv[src1] + adst + ae;
            al1 = a > 0.f ? a : 0.2f * a;
            aeloc += ae;
        }
    }
    float mloc = fmaxf(al0, al1);
    for (int base = start + 128; base < end; base += 64) {   // rare spill
        int j = base + lane;
        if (j < end) {
            float4 r = s_rec[j];
            float ae = (AEIDX == 0) ? r.x : r.y;
            int s = __float_as_int(r.z);
            float a = a_srcv[s] + adst + ae;
            a = a > 0.f ? a : 0.2f * a;
            mloc = fmaxf(mloc, a);
            aeloc += ae;
        }
    }
#pragma unroll
    for (int off = 32; off >= 1; off >>= 1) {
        mloc = fmaxf(mloc, __shfl_xor(mloc, off, 64));
        aeloc += __shfl_xor(aeloc, off, 64);
    }
    float ael = aeloc / (float)(deg > 0 ? deg : 1);
    float als = a_srcv[i] + adst + ael;
    als = als > 0.f ? als : 0.2f * als;
    float m = fmaxf(mloc, als);

    float w0 = (start + lane < end)      ? __expf(al0 - m) : 0.f;
    float w1 = (start + 64 + lane < end) ? __expf(al1 - m) : 0.f;
    float dloc = w0 + w1;
    for (int base = start + 128; base < end; base += 64) {   // rare spill
        int j = base + lane;
        if (j < end) {
            float4 r = s_rec[j];
            float ae = (AEIDX == 0) ? r.x : r.y;
            int s = __float_as_int(r.z);
            float a = a_srcv[s] + adst + ae;
            a = a > 0.f ? a : 0.2f * a;
            dloc += __expf(a - m);
        }
    }
#pragma unroll
    for (int off = 32; off >= 1; off >>= 1) dloc += __shfl_xor(dloc, off, 64);
    float wself = __expf(als - m);
    float inv = 1.f / (dloc + wself + 1e-16f);

    // ---- phase 2: gather. wave = 4 edge-slots x 16 channel-quads ----
    int sub = lane >> 4;          // edge slot 0..3
    int c4  = lane & 15;          // channel quad
    float4 acc = make_float4(0.f, 0.f, 0.f, 0.f);
    int mainCnt = deg < 128 ? deg : 128;
    for (int r = 0; r < mainCnt; r += 4) {
        int rel = r + sub;                 // 0..127 (may overrun tail: w==0 there)
        float wa = __shfl(w0, rel & 63, 64);
        float wb = __shfl(w1, rel & 63, 64);
        int   sa = __shfl(src0, rel & 63, 64);
        int   sb = __shfl(src1, rel & 63, 64);
        float w = (rel < 64) ? wa : wb;
        int   s = (rel < 64) ? sa : sb;
        float4 hv = H4[(size_t)s * 16 + c4];
        acc.x += w * hv.x; acc.y += w * hv.y;
        acc.z += w * hv.z; acc.w += w * hv.w;
    }
    for (int j = start + 128; j < end; j += 4) {   // rare spill: recompute w
        int jj = j + sub;
        if (jj < end) {
            float4 r = s_rec[jj];
            float ae = (AEIDX == 0) ? r.x : r.y;
            int s = __float_as_int(r.z);
            float a = a_srcv[s] + adst + ae;
            a = a > 0.f ? a : 0.2f * a;
            float w = __expf(a - m);
            float4 hv = H4[(size_t)s * 16 + c4];
            acc.x += w * hv.x; acc.y += w * hv.y;
            acc.z += w * hv.z; acc.w += w * hv.w;
        }
    }
    // reduce across the 4 edge-slots (lanes differing in bits 4,5)
#pragma unroll
    for (int off = 16; off <= 32; off <<= 1) {
        acc.x += __shfl_xor(acc.x, off, 64);
        acc.y += __shfl_xor(acc.y, off, 64);
        acc.z += __shfl_xor(acc.z, off, 64);
        acc.w += __shfl_xor(acc.w, off, 64);
    }
    // self-loop + epilogue (all lanes consistent)
    float4 hv = H4[(size_t)i * 16 + c4];
    float4 bv = ((const float4*)bias)[c4];
    float4 o;
    o.x = (acc.x + wself * hv.x) * inv + bv.x;
    o.y = (acc.y + wself * hv.y) * inv + bv.y;
    o.z = (acc.z + wself * hv.z) * inv + bv.z;
    o.w = (acc.w + wself * hv.w) * inv + bv.w;
    if (RELU) {
        o.x = fmaxf(o.x, 0.f); o.y = fmaxf(o.y, 0.f);
        o.z = fmaxf(o.z, 0.f); o.w = fmaxf(o.w, 0.f);
    }
    if (sub == 0) ((float4*)out)[(size_t)i * 16 + c4] = o;
}

// ---------------------------------------------------------------------------
extern "C" void kernel_launch(void* const* d_in, const int* in_sizes, int n_in,
                              void* d_out, int out_size, void* d_ws, size_t ws_size,
                              hipStream_t stream) {
    const float* x        = (const float*)d_in[0];
    const int*   eidx     = (const int*)d_in[1];
    const float* eattr    = (const float*)d_in[2];
    const float* W1       = (const float*)d_in[3];
    const float* We1      = (const float*)d_in[4];
    const float* att_src1 = (const float*)d_in[5];
    const float* att_dst1 = (const float*)d_in[6];
    const float* att_edge1= (const float*)d_in[7];
    const float* b1       = (const float*)d_in[8];
    const float* W2       = (const float*)d_in[9];
    const float* We2      = (const float*)d_in[10];
    const float* att_src2 = (const float*)d_in[11];
    const float* att_dst2 = (const float*)d_in[12];
    const float* att_edge2= (const float*)d_in[13];
    const float* b2       = (const float*)d_in[14];
    float* out = (float*)d_out;

    const int n = in_sizes[0] / 128;    // 50000
    const int E = in_sizes[1] / 2;      // 1600000

    char* ws = (char*)d_ws;
    size_t off = 0;
    auto carve = [&](size_t bytes) {
        char* p = ws + off;
        off = (off + bytes + 255) & ~(size_t)255;
        return p;
    };
    const int nblkScan = (n + 255) / 256;
    float*  we1    = (float*)carve(32 * 4);
    float*  we2    = (float*)carve(32 * 4);
    int*    cnt    = (int*)carve((size_t)n * 4);
    int*    bsum   = (int*)carve((size_t)nblkScan * 4);
    int*    boff   = (int*)carve((size_t)nblkScan * 4);
    int*    row_ptr= (int*)carve((size_t)(n + 1) * 4);
    float4* s_tmp  = (float4*)carve((size_t)E * 16);
    float4* s_rec  = (float4*)carve((size_t)E * 16);
    float*  bufA   = (float*)carve((size_t)n * 64 * 4);  // H (both layers)
    float*  bufB   = (float*)carve((size_t)n * 64 * 4);  // relu(gat1 out)
    float*  a_src  = (float*)carve((size_t)n * 4);
    float*  a_dst  = (float*)carve((size_t)n * 4);

    zero_kernel<<<nblkScan, 256, 0, stream>>>(cnt, n);

    we_kernel<<<1, 64, 0, stream>>>(We1, att_edge1, We2, att_edge2, we1, we2);

    int egrid = (E + 255) / 256;
    edge_pass_kernel<<<egrid, 256, 0, stream>>>((const float4*)eattr, eidx,
                                                we1, we2, cnt, s_tmp, E);
    scanA_kernel<<<nblkScan, 256, 0, stream>>>(cnt, bsum, n);
    scanB_kernel<<<1, 64, 0, stream>>>(bsum, boff, nblkScan);
    scanC_kernel<<<nblkScan, 256, 0, stream>>>(cnt, boff, row_ptr, n, E);

    scatter_kernel<<<egrid, 256, 0, stream>>>(s_tmp, row_ptr, s_rec, E);

    int ngrid = (n + 3) / 4;
    // layer 1
    gemm_kernel<128><<<ngrid, 256, 0, stream>>>(x, W1, att_src1, att_dst1,
                                                bufA, a_src, a_dst, n);
    agg_fused_kernel<0, true><<<ngrid, 256, 0, stream>>>(row_ptr, s_rec, a_src,
                                                         a_dst, (const float4*)bufA,
                                                         b1, bufB, n);
    // layer 2
    gemm_kernel<64><<<ngrid, 256, 0, stream>>>(bufB, W2, att_src2, att_dst2,
                                               bufA, a_src, a_dst, n);
    agg_fused_kernel<1, false><<<ngrid, 256, 0, stream>>>(row_ptr, s_rec, a_src,
                                                          a_dst, (const float4*)bufA,
                                                          b2, out, n);
}

// Round 8
// 328.178 us; speedup vs baseline: 2.3068x; 1.0712x over previous
//
#include <hip/hip_runtime.h>
#include <hip/hip_bf16.h>

// ---------------------------------------------------------------------------
// zero cnt
// ---------------------------------------------------------------------------
__global__ __launch_bounds__(256)
void zero_kernel(int* __restrict__ p, int n) {
    int i = blockIdx.x * 256 + threadIdx.x;
    if (i < n) p[i] = 0;
}

// ---------------------------------------------------------------------------
// we[k] = sum_c We[k][c] * att_edge[c]  (per layer, 32 values each)
// ---------------------------------------------------------------------------
__global__ void we_kernel(const float* __restrict__ We1, const float* __restrict__ ae1v,
                          const float* __restrict__ We2, const float* __restrict__ ae2v,
                          float* __restrict__ we1, float* __restrict__ we2) {
    int t = threadIdx.x;            // 64 threads
    const float* W = (t < 32) ? We1 : We2;
    const float* a = (t < 32) ? ae1v : ae2v;
    float* o       = (t < 32) ? we1 : we2;
    int k = t & 31;
    float s = 0.f;
    for (int c = 0; c < 64; ++c) s += W[k * 64 + c] * a[c];
    o[k] = s;
}

// ---------------------------------------------------------------------------
// fused streaming pass: edge-attr dot (both layers) + in-degree rank.
// ALL reads/writes sequential. record = {ae1, ae2, src_bits, (rank<<16)|dst}
// ---------------------------------------------------------------------------
__global__ __launch_bounds__(256)
void edge_pass_kernel(const float4* __restrict__ ea, const int* __restrict__ eidx,
                      const float* __restrict__ we1g, const float* __restrict__ we2g,
                      int* __restrict__ cnt, float4* __restrict__ s_tmp, int E) {
    __shared__ float w1s[32], w2s[32];
    if (threadIdx.x < 32) w1s[threadIdx.x] = we1g[threadIdx.x];
    else if (threadIdx.x < 64) w2s[threadIdx.x - 32] = we2g[threadIdx.x - 32];
    __syncthreads();
    int e = blockIdx.x * 256 + threadIdx.x;
    if (e >= E) return;
    float acc1 = 0.f, acc2 = 0.f;
#pragma unroll
    for (int q = 0; q < 8; ++q) {
        float4 v = ea[(size_t)e * 8 + q];
        acc1 += v.x * w1s[q * 4 + 0] + v.y * w1s[q * 4 + 1] +
                v.z * w1s[q * 4 + 2] + v.w * w1s[q * 4 + 3];
        acc2 += v.x * w2s[q * 4 + 0] + v.y * w2s[q * 4 + 1] +
                v.z * w2s[q * 4 + 2] + v.w * w2s[q * 4 + 3];
    }
    int src = eidx[e];
    int dst = eidx[E + e];
    int rk = atomicAdd(&cnt[dst], 1);           // rank within dst segment
    unsigned packed = ((unsigned)rk << 16) | (unsigned)dst;
    s_tmp[e] = make_float4(acc1, acc2, __int_as_float(src),
                           __int_as_float((int)packed));
}

// ---------------------------------------------------------------------------
// scan stage A: per-256-chunk sums
// ---------------------------------------------------------------------------
__global__ __launch_bounds__(256)
void scanA_kernel(const int* __restrict__ cnt, int* __restrict__ bsum, int n) {
    int idx = blockIdx.x * 256 + threadIdx.x;
    int v = (idx < n) ? cnt[idx] : 0;
#pragma unroll
    for (int off = 32; off >= 1; off >>= 1) v += __shfl_xor(v, off, 64);
    __shared__ int ws[4];
    int lane = threadIdx.x & 63, wid = threadIdx.x >> 6;
    if (lane == 0) ws[wid] = v;
    __syncthreads();
    if (threadIdx.x == 0) bsum[blockIdx.x] = ws[0] + ws[1] + ws[2] + ws[3];
}

// ---------------------------------------------------------------------------
// scan stage B: exclusive scan of chunk sums (single wave)
// ---------------------------------------------------------------------------
__global__ void scanB_kernel(const int* __restrict__ bsum, int* __restrict__ boff, int nb) {
    int lane = threadIdx.x;   // 64
    int carry = 0;
    for (int base = 0; base < nb; base += 64) {
        int idx = base + lane;
        int v = (idx < nb) ? bsum[idx] : 0;
        int s = v;
#pragma unroll
        for (int off = 1; off < 64; off <<= 1) {
            int t = __shfl_up(s, off, 64);
            if (lane >= off) s += t;
        }
        if (idx < nb) boff[idx] = carry + s - v;
        carry += __shfl(s, 63, 64);
    }
}

// ---------------------------------------------------------------------------
// scan stage C: in-chunk scan + chunk offset -> row_ptr
// ---------------------------------------------------------------------------
__global__ __launch_bounds__(256)
void scanC_kernel(const int* __restrict__ cnt, const int* __restrict__ boff,
                  int* __restrict__ row_ptr, int n, int E) {
    __shared__ int ws[4];
    __shared__ int woff[4];
    int idx = blockIdx.x * 256 + threadIdx.x;
    int lane = threadIdx.x & 63, wid = threadIdx.x >> 6;
    int v = (idx < n) ? cnt[idx] : 0;
    int s = v;
#pragma unroll
    for (int off = 1; off < 64; off <<= 1) {
        int t = __shfl_up(s, off, 64);
        if (lane >= off) s += t;
    }
    if (lane == 63) ws[wid] = s;
    __syncthreads();
    if (threadIdx.x == 0) {
        int run = 0;
        for (int w = 0; w < 4; ++w) { int t = ws[w]; woff[w] = run; run += t; }
    }
    __syncthreads();
    if (idx < n) row_ptr[idx] = boff[blockIdx.x] + woff[wid] + s - v;
    if (idx == 0) row_ptr[n] = E;
}

// ---------------------------------------------------------------------------
// scatter pass: sequential record read, single scattered 16B store.
// pos = row_ptr[dst] + rank (atomic-free, deterministic given ranks)
// ---------------------------------------------------------------------------
__global__ __launch_bounds__(256)
void scatter_kernel(const float4* __restrict__ s_tmp, const int* __restrict__ row_ptr,
                    float4* __restrict__ s_rec, int E) {
    int e = blockIdx.x * 256 + threadIdx.x;
    if (e >= E) return;
    float4 r = s_tmp[e];
    unsigned packed = (unsigned)__float_as_int(r.w);
    int dst = (int)(packed & 0xFFFFu);
    int rk  = (int)(packed >> 16);
    int pos = row_ptr[dst] + rk;
    s_rec[pos] = make_float4(r.x, r.y, r.z, 0.f);
}

// ---------------------------------------------------------------------------
// H = X @ W (one wave per node, lane = out channel) + attn logit dots.
// H is stored as bf16 (RN) - halves the gather traffic in agg.
// ---------------------------------------------------------------------------
template <int INC>
__global__ __launch_bounds__(256)
void gemm_kernel(const float* __restrict__ X, const float* __restrict__ W,
                 const float* __restrict__ asv, const float* __restrict__ adv,
                 __hip_bfloat16* __restrict__ H, float* __restrict__ a_src,
                 float* __restrict__ a_dst, int n) {
    __shared__ float Wl[INC * 64];
    for (int t = threadIdx.x; t < INC * 64; t += 256) Wl[t] = W[t];
    __syncthreads();
    int wid = threadIdx.x >> 6, lane = threadIdx.x & 63;
    int i = blockIdx.x * 4 + wid;
    if (i >= n) return;
    const float4* xr = (const float4*)(X + (size_t)i * INC);
    float acc = 0.f;
#pragma unroll
    for (int k4 = 0; k4 < INC / 4; ++k4) {
        float4 xv = xr[k4];
        acc += xv.x * Wl[(k4 * 4 + 0) * 64 + lane];
        acc += xv.y * Wl[(k4 * 4 + 1) * 64 + lane];
        acc += xv.z * Wl[(k4 * 4 + 2) * 64 + lane];
        acc += xv.w * Wl[(k4 * 4 + 3) * 64 + lane];
    }
    H[(size_t)i * 64 + lane] = __float2bfloat16(acc);   // RN pack, 2B store
    float s = acc * asv[lane];
    float d = acc * adv[lane];
#pragma unroll
    for (int off = 32; off >= 1; off >>= 1) {
        s += __shfl_xor(s, off, 64);
        d += __shfl_xor(d, off, 64);
    }
    if (lane == 0) { a_src[i] = s; a_dst[i] = d; }
}

// bf16x4 (ushort4, 8B) -> 4 floats via bit shift
__device__ __forceinline__ float4 bf4_to_f4(ushort4 u) {
    float4 f;
    f.x = __uint_as_float((unsigned)u.x << 16);
    f.y = __uint_as_float((unsigned)u.y << 16);
    f.z = __uint_as_float((unsigned)u.z << 16);
    f.w = __uint_as_float((unsigned)u.w << 16);
    return f;
}

// ---------------------------------------------------------------------------
// fused aggregation: softmax weights in registers (lane = edge), then
// gather phase as wave = 4 edge-slots x 16 channel-quads (bf16x4 = 8B loads)
// ---------------------------------------------------------------------------
template <int AEIDX, bool RELU>
__global__ __launch_bounds__(256)
void agg_fused_kernel(const int* __restrict__ row_ptr, const float4* __restrict__ s_rec,
                      const float* __restrict__ a_srcv, const float* __restrict__ a_dstv,
                      const ushort4* __restrict__ H4, const float* __restrict__ bias,
                      float* __restrict__ out, int n) {
    int wid = threadIdx.x >> 6, lane = threadIdx.x & 63;
    int i = blockIdx.x * 4 + wid;
    if (i >= n) return;
    int start = row_ptr[i], end = row_ptr[i + 1];
    int deg = end - start;
    float adst = a_dstv[i];

    // ---- phase 1: logits (lane = edge), deg<=128 fast path in regs ----
    float al0 = -INFINITY, al1 = -INFINITY;
    int src0 = 0, src1 = 0;
    float aeloc = 0.f;
    {
        int j = start + lane;
        if (j < end) {
            float4 r = s_rec[j];
            float ae = (AEIDX == 0) ? r.x : r.y;
            src0 = __float_as_int(r.z);
            float a = a_srcv[src0] + adst + ae;
            al0 = a > 0.f ? a : 0.2f * a;
            aeloc += ae;
        }
    }
    if (deg > 64) {
        int j = start + 64 + lane;
        if (j < end) {
            float4 r = s_rec[j];
            float ae = (AEIDX == 0) ? r.x : r.y;
            src1 = __float_as_int(r.z);
            float a = a_srcv[src1] + adst + ae;
            al1 = a > 0.f ? a : 0.2f * a;
            aeloc += ae;
        }
    }
    float mloc = fmaxf(al0, al1);
    for (int base = start + 128; base < end; base += 64) {   // rare spill
        int j = base + lane;
        if (j < end) {
            float4 r = s_rec[j];
            float ae = (AEIDX == 0) ? r.x : r.y;
            int s = __float_as_int(r.z);
            float a = a_srcv[s] + adst + ae;
            a = a > 0.f ? a : 0.2f * a;
            mloc = fmaxf(mloc, a);
            aeloc += ae;
        }
    }
#pragma unroll
    for (int off = 32; off >= 1; off >>= 1) {
        mloc = fmaxf(mloc, __shfl_xor(mloc, off, 64));
        aeloc += __shfl_xor(aeloc, off, 64);
    }
    float ael = aeloc / (float)(deg > 0 ? deg : 1);
    float als = a_srcv[i] + adst + ael;
    als = als > 0.f ? als : 0.2f * als;
    float m = fmaxf(mloc, als);

    float w0 = (start + lane < end)      ? __expf(al0 - m) : 0.f;
    float w1 = (start + 64 + lane < end) ? __expf(al1 - m) : 0.f;
    float dloc = w0 + w1;
    for (int base = start + 128; base < end; base += 64) {   // rare spill
        int j = base + lane;
        if (j < end) {
            float4 r = s_rec[j];
            float ae = (AEIDX == 0) ? r.x : r.y;
            int s = __float_as_int(r.z);
            float a = a_srcv[s] + adst + ae;
            a = a > 0.f ? a : 0.2f * a;
            dloc += __expf(a - m);
        }
    }
#pragma unroll
    for (int off = 32; off >= 1; off >>= 1) dloc += __shfl_xor(dloc, off, 64);
    float wself = __expf(als - m);
    float inv = 1.f / (dloc + wself + 1e-16f);

    // ---- phase 2: gather. wave = 4 edge-slots x 16 channel-quads ----
    int sub = lane >> 4;          // edge slot 0..3
    int c4  = lane & 15;          // channel quad
    float4 acc = make_float4(0.f, 0.f, 0.f, 0.f);
    int mainCnt = deg < 128 ? deg : 128;
    for (int r = 0; r < mainCnt; r += 4) {
        int rel = r + sub;                 // 0..127 (may overrun tail: w==0 there)
        float wa = __shfl(w0, rel & 63, 64);
        float wb = __shfl(w1, rel & 63, 64);
        int   sa = __shfl(src0, rel & 63, 64);
        int   sb = __shfl(src1, rel & 63, 64);
        float w = (rel < 64) ? wa : wb;
        int   s = (rel < 64) ? sa : sb;
        float4 hv = bf4_to_f4(H4[(size_t)s * 16 + c4]);
        acc.x += w * hv.x; acc.y += w * hv.y;
        acc.z += w * hv.z; acc.w += w * hv.w;
    }
    for (int j = start + 128; j < end; j += 4) {   // rare spill: recompute w
        int jj = j + sub;
        if (jj < end) {
            float4 r = s_rec[jj];
            float ae = (AEIDX == 0) ? r.x : r.y;
            int s = __float_as_int(r.z);
            float a = a_srcv[s] + adst + ae;
            a = a > 0.f ? a : 0.2f * a;
            float w = __expf(a - m);
            float4 hv = bf4_to_f4(H4[(size_t)s * 16 + c4]);
            acc.x += w * hv.x; acc.y += w * hv.y;
            acc.z += w * hv.z; acc.w += w * hv.w;
        }
    }
    // reduce across the 4 edge-slots (lanes differing in bits 4,5)
#pragma unroll
    for (int off = 16; off <= 32; off <<= 1) {
        acc.x += __shfl_xor(acc.x, off, 64);
        acc.y += __shfl_xor(acc.y, off, 64);
        acc.z += __shfl_xor(acc.z, off, 64);
        acc.w += __shfl_xor(acc.w, off, 64);
    }
    // self-loop + epilogue (all lanes consistent)
    float4 hv = bf4_to_f4(H4[(size_t)i * 16 + c4]);
    float4 bv = ((const float4*)bias)[c4];
    float4 o;
    o.x = (acc.x + wself * hv.x) * inv + bv.x;
    o.y = (acc.y + wself * hv.y) * inv + bv.y;
    o.z = (acc.z + wself * hv.z) * inv + bv.z;
    o.w = (acc.w + wself * hv.w) * inv + bv.w;
    if (RELU) {
        o.x = fmaxf(o.x, 0.f); o.y = fmaxf(o.y, 0.f);
        o.z = fmaxf(o.z, 0.f); o.w = fmaxf(o.w, 0.f);
    }
    if (sub == 0) ((float4*)out)[(size_t)i * 16 + c4] = o;
}

// ---------------------------------------------------------------------------
extern "C" void kernel_launch(void* const* d_in, const int* in_sizes, int n_in,
                              void* d_out, int out_size, void* d_ws, size_t ws_size,
                              hipStream_t stream) {
    const float* x        = (const float*)d_in[0];
    const int*   eidx     = (const int*)d_in[1];
    const float* eattr    = (const float*)d_in[2];
    const float* W1       = (const float*)d_in[3];
    const float* We1      = (const float*)d_in[4];
    const float* att_src1 = (const float*)d_in[5];
    const float* att_dst1 = (const float*)d_in[6];
    const float* att_edge1= (const float*)d_in[7];
    const float* b1       = (const float*)d_in[8];
    const float* W2       = (const float*)d_in[9];
    const float* We2      = (const float*)d_in[10];
    const float* att_src2 = (const float*)d_in[11];
    const float* att_dst2 = (const float*)d_in[12];
    const float* att_edge2= (const float*)d_in[13];
    const float* b2       = (const float*)d_in[14];
    float* out = (float*)d_out;

    const int n = in_sizes[0] / 128;    // 50000
    const int E = in_sizes[1] / 2;      // 1600000

    char* ws = (char*)d_ws;
    size_t off = 0;
    auto carve = [&](size_t bytes) {
        char* p = ws + off;
        off = (off + bytes + 255) & ~(size_t)255;
        return p;
    };
    const int nblkScan = (n + 255) / 256;
    float*  we1    = (float*)carve(32 * 4);
    float*  we2    = (float*)carve(32 * 4);
    int*    cnt    = (int*)carve((size_t)n * 4);
    int*    bsum   = (int*)carve((size_t)nblkScan * 4);
    int*    boff   = (int*)carve((size_t)nblkScan * 4);
    int*    row_ptr= (int*)carve((size_t)(n + 1) * 4);
    float4* s_tmp  = (float4*)carve((size_t)E * 16);
    float4* s_rec  = (float4*)carve((size_t)E * 16);
    __hip_bfloat16* bufA = (__hip_bfloat16*)carve((size_t)n * 64 * 2);  // H bf16
    float*  bufB   = (float*)carve((size_t)n * 64 * 4);  // relu(gat1 out) f32
    float*  a_src  = (float*)carve((size_t)n * 4);
    float*  a_dst  = (float*)carve((size_t)n * 4);

    zero_kernel<<<nblkScan, 256, 0, stream>>>(cnt, n);

    we_kernel<<<1, 64, 0, stream>>>(We1, att_edge1, We2, att_edge2, we1, we2);

    int egrid = (E + 255) / 256;
    edge_pass_kernel<<<egrid, 256, 0, stream>>>((const float4*)eattr, eidx,
                                                we1, we2, cnt, s_tmp, E);
    scanA_kernel<<<nblkScan, 256, 0, stream>>>(cnt, bsum, n);
    scanB_kernel<<<1, 64, 0, stream>>>(bsum, boff, nblkScan);
    scanC_kernel<<<nblkScan, 256, 0, stream>>>(cnt, boff, row_ptr, n, E);

    scatter_kernel<<<egrid, 256, 0, stream>>>(s_tmp, row_ptr, s_rec, E);

    int ngrid = (n + 3) / 4;
    // layer 1
    gemm_kernel<128><<<ngrid, 256, 0, stream>>>(x, W1, att_src1, att_dst1,
                                                bufA, a_src, a_dst, n);
    agg_fused_kernel<0, true><<<ngrid, 256, 0, stream>>>(row_ptr, s_rec, a_src,
                                                         a_dst, (const ushort4*)bufA,
                                                         b1, bufB, n);
    // layer 2
    gemm_kernel<64><<<ngrid, 256, 0, stream>>>(bufB, W2, att_src2, att_dst2,
                                               bufA, a_src, a_dst, n);
    agg_fused_kernel<1, false><<<ngrid, 256, 0, stream>>>(row_ptr, s_rec, a_src,
                                                          a_dst, (const ushort4*)bufA,
                                                          b2, out, n);
}

// Round 9
// 299.554 us; speedup vs baseline: 2.5272x; 1.0956x over previous
//
#include <hip/hip_runtime.h>
#include <hip/hip_bf16.h>

// bf16 round-to-nearest-even pack / unpack (bit ops, no type gymnastics)
__device__ __forceinline__ unsigned f2bf_rne(float f) {
    unsigned u = __float_as_uint(f);
    u += 0x7FFFu + ((u >> 16) & 1u);
    return u >> 16;
}
__device__ __forceinline__ float bf_lo(unsigned p) { return __uint_as_float(p << 16); }
__device__ __forceinline__ float bf_hi(unsigned p) { return __uint_as_float(p & 0xFFFF0000u); }
template <int I> __device__ __forceinline__ float bfsel(unsigned p) {
    return (I == 0) ? bf_lo(p) : bf_hi(p);
}

// ---------------------------------------------------------------------------
// zero cnt
// ---------------------------------------------------------------------------
__global__ __launch_bounds__(256)
void zero_kernel(int* __restrict__ p, int n) {
    int i = blockIdx.x * 256 + threadIdx.x;
    if (i < n) p[i] = 0;
}

// ---------------------------------------------------------------------------
// we[k] = sum_c We[k][c] * att_edge[c]  (per layer, 32 values each)
// ---------------------------------------------------------------------------
__global__ void we_kernel(const float* __restrict__ We1, const float* __restrict__ ae1v,
                          const float* __restrict__ We2, const float* __restrict__ ae2v,
                          float* __restrict__ we1, float* __restrict__ we2) {
    int t = threadIdx.x;            // 64 threads
    const float* W = (t < 32) ? We1 : We2;
    const float* a = (t < 32) ? ae1v : ae2v;
    float* o       = (t < 32) ? we1 : we2;
    int k = t & 31;
    float s = 0.f;
    for (int c = 0; c < 64; ++c) s += W[k * 64 + c] * a[c];
    o[k] = s;
}

// ---------------------------------------------------------------------------
// streaming edge pass, 8 lanes per edge (perfectly coalesced 16B/lane):
// dot(ea, we) for both layers + in-degree rank.
// pack8[e] = {src, bf16(ae1) | bf16(ae2)<<16};  meta[e] = rank<<16 | dst
// ---------------------------------------------------------------------------
__global__ __launch_bounds__(256)
void edge_pass_kernel(const float4* __restrict__ ea, const int* __restrict__ eidx,
                      const float* __restrict__ we1g, const float* __restrict__ we2g,
                      int* __restrict__ cnt, uint2* __restrict__ pack8,
                      unsigned* __restrict__ meta, int E) {
    int tid = threadIdx.x;
    int q = tid & 7;                          // float4-quad within edge
    int e = blockIdx.x * 32 + (tid >> 3);     // 32 edges per block
    if (e >= E) return;
    float4 w1 = ((const float4*)we1g)[q];
    float4 w2 = ((const float4*)we2g)[q];
    float4 v = ea[(size_t)e * 8 + q];
    float a1 = v.x * w1.x + v.y * w1.y + v.z * w1.z + v.w * w1.w;
    float a2 = v.x * w2.x + v.y * w2.y + v.z * w2.z + v.w * w2.w;
#pragma unroll
    for (int off = 1; off < 8; off <<= 1) {
        a1 += __shfl_xor(a1, off, 64);
        a2 += __shfl_xor(a2, off, 64);
    }
    if (q == 0) {
        int src = eidx[e];
        int dst = eidx[E + e];
        int rk = atomicAdd(&cnt[dst], 1);
        pack8[e] = make_uint2((unsigned)src, f2bf_rne(a1) | (f2bf_rne(a2) << 16));
        meta[e] = ((unsigned)rk << 16) | (unsigned)dst;
    }
}

// ---------------------------------------------------------------------------
// scan stage A: per-256-chunk sums
// ---------------------------------------------------------------------------
__global__ __launch_bounds__(256)
void scanA_kernel(const int* __restrict__ cnt, int* __restrict__ bsum, int n) {
    int idx = blockIdx.x * 256 + threadIdx.x;
    int v = (idx < n) ? cnt[idx] : 0;
#pragma unroll
    for (int off = 32; off >= 1; off >>= 1) v += __shfl_xor(v, off, 64);
    __shared__ int ws[4];
    int lane = threadIdx.x & 63, wid = threadIdx.x >> 6;
    if (lane == 0) ws[wid] = v;
    __syncthreads();
    if (threadIdx.x == 0) bsum[blockIdx.x] = ws[0] + ws[1] + ws[2] + ws[3];
}

// ---------------------------------------------------------------------------
// scan stage B: exclusive scan of chunk sums (single wave)
// ---------------------------------------------------------------------------
__global__ void scanB_kernel(const int* __restrict__ bsum, int* __restrict__ boff, int nb) {
    int lane = threadIdx.x;   // 64
    int carry = 0;
    for (int base = 0; base < nb; base += 64) {
        int idx = base + lane;
        int v = (idx < nb) ? bsum[idx] : 0;
        int s = v;
#pragma unroll
        for (int off = 1; off < 64; off <<= 1) {
            int t = __shfl_up(s, off, 64);
            if (lane >= off) s += t;
        }
        if (idx < nb) boff[idx] = carry + s - v;
        carry += __shfl(s, 63, 64);
    }
}

// ---------------------------------------------------------------------------
// scan stage C: in-chunk scan + chunk offset -> row_ptr
// ---------------------------------------------------------------------------
__global__ __launch_bounds__(256)
void scanC_kernel(const int* __restrict__ cnt, const int* __restrict__ boff,
                  int* __restrict__ row_ptr, int n, int E) {
    __shared__ int ws[4];
    __shared__ int woff[4];
    int idx = blockIdx.x * 256 + threadIdx.x;
    int lane = threadIdx.x & 63, wid = threadIdx.x >> 6;
    int v = (idx < n) ? cnt[idx] : 0;
    int s = v;
#pragma unroll
    for (int off = 1; off < 64; off <<= 1) {
        int t = __shfl_up(s, off, 64);
        if (lane >= off) s += t;
    }
    if (lane == 63) ws[wid] = s;
    __syncthreads();
    if (threadIdx.x == 0) {
        int run = 0;
        for (int w = 0; w < 4; ++w) { int t = ws[w]; woff[w] = run; run += t; }
    }
    __syncthreads();
    if (idx < n) row_ptr[idx] = boff[blockIdx.x] + woff[wid] + s - v;
    if (idx == 0) row_ptr[n] = E;
}

// ---------------------------------------------------------------------------
// scatter pass: sequential 12B read, single scattered 8B store.
// pos = row_ptr[dst] + rank (atomic-free, deterministic)
// ---------------------------------------------------------------------------
__global__ __launch_bounds__(256)
void scatter_kernel(const uint2* __restrict__ pack8, const unsigned* __restrict__ meta,
                    const int* __restrict__ row_ptr, uint2* __restrict__ s_rec, int E) {
    int e = blockIdx.x * 256 + threadIdx.x;
    if (e >= E) return;
    unsigned m = meta[e];
    int dst = (int)(m & 0xFFFFu);
    int rk  = (int)(m >> 16);
    s_rec[row_ptr[dst] + rk] = pack8[e];
}

// ---------------------------------------------------------------------------
// H = X @ W (one wave per node, lane = out channel) + attn logit dots.
// H stored bf16 (halves gather traffic).
// ---------------------------------------------------------------------------
template <int INC>
__global__ __launch_bounds__(256)
void gemm_kernel(const float* __restrict__ X, const float* __restrict__ W,
                 const float* __restrict__ asv, const float* __restrict__ adv,
                 __hip_bfloat16* __restrict__ H, float* __restrict__ a_src,
                 float* __restrict__ a_dst, int n) {
    __shared__ float Wl[INC * 64];
    for (int t = threadIdx.x; t < INC * 64; t += 256) Wl[t] = W[t];
    __syncthreads();
    int wid = threadIdx.x >> 6, lane = threadIdx.x & 63;
    int i = blockIdx.x * 4 + wid;
    if (i >= n) return;
    const float4* xr = (const float4*)(X + (size_t)i * INC);
    float acc = 0.f;
#pragma unroll
    for (int k4 = 0; k4 < INC / 4; ++k4) {
        float4 xv = xr[k4];
        acc += xv.x * Wl[(k4 * 4 + 0) * 64 + lane];
        acc += xv.y * Wl[(k4 * 4 + 1) * 64 + lane];
        acc += xv.z * Wl[(k4 * 4 + 2) * 64 + lane];
        acc += xv.w * Wl[(k4 * 4 + 3) * 64 + lane];
    }
    H[(size_t)i * 64 + lane] = __float2bfloat16(acc);
    float s = acc * asv[lane];
    float d = acc * adv[lane];
#pragma unroll
    for (int off = 32; off >= 1; off >>= 1) {
        s += __shfl_xor(s, off, 64);
        d += __shfl_xor(d, off, 64);
    }
    if (lane == 0) { a_src[i] = s; a_dst[i] = d; }
}

// bf16x4 (ushort4, 8B) -> 4 floats
__device__ __forceinline__ float4 bf4_to_f4(ushort4 u) {
    float4 f;
    f.x = __uint_as_float((unsigned)u.x << 16);
    f.y = __uint_as_float((unsigned)u.y << 16);
    f.z = __uint_as_float((unsigned)u.z << 16);
    f.w = __uint_as_float((unsigned)u.w << 16);
    return f;
}

// ---------------------------------------------------------------------------
// fused aggregation: softmax weights (lane = edge) -> wave-private LDS;
// gather phase wave = 4 edge-slots x 16 channel-quads, LDS b64 broadcast.
// ---------------------------------------------------------------------------
template <int AEIDX, bool RELU>
__global__ __launch_bounds__(256)
void agg_fused_kernel(const int* __restrict__ row_ptr, const uint2* __restrict__ s_rec,
                      const float* __restrict__ a_srcv, const float* __restrict__ a_dstv,
                      const ushort4* __restrict__ H4, const float* __restrict__ bias,
                      float* __restrict__ out, int n) {
    __shared__ uint2 wl[4][128];
    int wid = threadIdx.x >> 6, lane = threadIdx.x & 63;
    int i = blockIdx.x * 4 + wid;
    if (i >= n) return;
    int start = row_ptr[i], end = row_ptr[i + 1];
    int deg = end - start;
    float adst = a_dstv[i];

    // ---- phase 1: logits (lane = edge), deg<=128 fast path in regs ----
    float al0 = -INFINITY, al1 = -INFINITY;
    int src0 = 0, src1 = 0;
    float aeloc = 0.f;
    {
        int j = start + lane;
        if (j < end) {
            uint2 r = s_rec[j];
            float ae = bfsel<AEIDX>(r.y);
            src0 = (int)r.x;
            float a = a_srcv[src0] + adst + ae;
            al0 = a > 0.f ? a : 0.2f * a;
            aeloc += ae;
        }
    }
    if (deg > 64) {
        int j = start + 64 + lane;
        if (j < end) {
            uint2 r = s_rec[j];
            float ae = bfsel<AEIDX>(r.y);
            src1 = (int)r.x;
            float a = a_srcv[src1] + adst + ae;
            al1 = a > 0.f ? a : 0.2f * a;
            aeloc += ae;
        }
    }
    float mloc = fmaxf(al0, al1);
    for (int base = start + 128; base < end; base += 64) {   // rare spill
        int j = base + lane;
        if (j < end) {
            uint2 r = s_rec[j];
            float ae = bfsel<AEIDX>(r.y);
            int s = (int)r.x;
            float a = a_srcv[s] + adst + ae;
            a = a > 0.f ? a : 0.2f * a;
            mloc = fmaxf(mloc, a);
            aeloc += ae;
        }
    }
#pragma unroll
    for (int off = 32; off >= 1; off >>= 1) {
        mloc = fmaxf(mloc, __shfl_xor(mloc, off, 64));
        aeloc += __shfl_xor(aeloc, off, 64);
    }
    float ael = aeloc / (float)(deg > 0 ? deg : 1);
    float als = a_srcv[i] + adst + ael;
    als = als > 0.f ? als : 0.2f * als;
    float m = fmaxf(mloc, als);

    float w0 = (start + lane < end)      ? __expf(al0 - m) : 0.f;
    float w1 = (start + 64 + lane < end) ? __expf(al1 - m) : 0.f;
    float dloc = w0 + w1;
    for (int base = start + 128; base < end; base += 64) {   // rare spill
        int j = base + lane;
        if (j < end) {
            uint2 r = s_rec[j];
            float ae = bfsel<AEIDX>(r.y);
            int s = (int)r.x;
            float a = a_srcv[s] + adst + ae;
            a = a > 0.f ? a : 0.2f * a;
            dloc += __expf(a - m);
        }
    }
#pragma unroll
    for (int off = 32; off >= 1; off >>= 1) dloc += __shfl_xor(dloc, off, 64);
    float wself = __expf(als - m);
    float inv = 1.f / (dloc + wself + 1e-16f);

    // stage {src, w} in wave-private LDS (slots beyond deg carry w=0)
    wl[wid][lane]      = make_uint2((unsigned)src0, __float_as_uint(w0));
    wl[wid][64 + lane] = make_uint2((unsigned)src1, __float_as_uint(w1));

    // ---- phase 2: gather. wave = 4 edge-slots x 16 channel-quads ----
    int sub = lane >> 4;          // edge slot 0..3
    int c4  = lane & 15;          // channel quad
    float4 acc = make_float4(0.f, 0.f, 0.f, 0.f);
    int mainCnt = deg < 128 ? deg : 128;
#pragma unroll 4
    for (int r = 0; r < mainCnt; r += 4) {
        uint2 sw = wl[wid][r + sub];             // 8B LDS broadcast
        float w = __uint_as_float(sw.y);
        float4 hv = bf4_to_f4(H4[(size_t)sw.x * 16 + c4]);
        acc.x += w * hv.x; acc.y += w * hv.y;
        acc.z += w * hv.z; acc.w += w * hv.w;
    }
    for (int j = start + 128; j < end; j += 4) {   // rare spill: recompute w
        int jj = j + sub;
        if (jj < end) {
            uint2 r = s_rec[jj];
            float ae = bfsel<AEIDX>(r.y);
            int s = (int)r.x;
            float a = a_srcv[s] + adst + ae;
            a = a > 0.f ? a : 0.2f * a;
            float w = __expf(a - m);
            float4 hv = bf4_to_f4(H4[(size_t)s * 16 + c4]);
            acc.x += w * hv.x; acc.y += w * hv.y;
            acc.z += w * hv.z; acc.w += w * hv.w;
        }
    }
    // reduce across the 4 edge-slots (lanes differing in bits 4,5)
#pragma unroll
    for (int off = 16; off <= 32; off <<= 1) {
        acc.x += __shfl_xor(acc.x, off, 64);
        acc.y += __shfl_xor(acc.y, off, 64);
        acc.z += __shfl_xor(acc.z, off, 64);
        acc.w += __shfl_xor(acc.w, off, 64);
    }
    // self-loop + epilogue
    float4 hv = bf4_to_f4(H4[(size_t)i * 16 + c4]);
    float4 bv = ((const float4*)bias)[c4];
    float4 o;
    o.x = (acc.x + wself * hv.x) * inv + bv.x;
    o.y = (acc.y + wself * hv.y) * inv + bv.y;
    o.z = (acc.z + wself * hv.z) * inv + bv.z;
    o.w = (acc.w + wself * hv.w) * inv + bv.w;
    if (RELU) {
        o.x = fmaxf(o.x, 0.f); o.y = fmaxf(o.y, 0.f);
        o.z = fmaxf(o.z, 0.f); o.w = fmaxf(o.w, 0.f);
    }
    if (sub == 0) ((float4*)out)[(size_t)i * 16 + c4] = o;
}

// ---------------------------------------------------------------------------
extern "C" void kernel_launch(void* const* d_in, const int* in_sizes, int n_in,
                              void* d_out, int out_size, void* d_ws, size_t ws_size,
                              hipStream_t stream) {
    const float* x        = (const float*)d_in[0];
    const int*   eidx     = (const int*)d_in[1];
    const float* eattr    = (const float*)d_in[2];
    const float* W1       = (const float*)d_in[3];
    const float* We1      = (const float*)d_in[4];
    const float* att_src1 = (const float*)d_in[5];
    const float* att_dst1 = (const float*)d_in[6];
    const float* att_edge1= (const float*)d_in[7];
    const float* b1       = (const float*)d_in[8];
    const float* W2       = (const float*)d_in[9];
    const float* We2      = (const float*)d_in[10];
    const float* att_src2 = (const float*)d_in[11];
    const float* att_dst2 = (const float*)d_in[12];
    const float* att_edge2= (const float*)d_in[13];
    const float* b2       = (const float*)d_in[14];
    float* out = (float*)d_out;

    const int n = in_sizes[0] / 128;    // 50000
    const int E = in_sizes[1] / 2;      // 1600000

    char* ws = (char*)d_ws;
    size_t off = 0;
    auto carve = [&](size_t bytes) {
        char* p = ws + off;
        off = (off + bytes + 255) & ~(size_t)255;
        return p;
    };
    const int nblkScan = (n + 255) / 256;
    float*    we1    = (float*)carve(32 * 4);
    float*    we2    = (float*)carve(32 * 4);
    int*      cnt    = (int*)carve((size_t)n * 4);
    int*      bsum   = (int*)carve((size_t)nblkScan * 4);
    int*      boff   = (int*)carve((size_t)nblkScan * 4);
    int*      row_ptr= (int*)carve((size_t)(n + 1) * 4);
    uint2*    pack8  = (uint2*)carve((size_t)E * 8);
    unsigned* meta   = (unsigned*)carve((size_t)E * 4);
    uint2*    s_rec  = (uint2*)carve((size_t)E * 8);
    __hip_bfloat16* bufA = (__hip_bfloat16*)carve((size_t)n * 64 * 2);  // H bf16
    float*    bufB   = (float*)carve((size_t)n * 64 * 4);  // relu(gat1 out) f32
    float*    a_src  = (float*)carve((size_t)n * 4);
    float*    a_dst  = (float*)carve((size_t)n * 4);

    zero_kernel<<<nblkScan, 256, 0, stream>>>(cnt, n);

    we_kernel<<<1, 64, 0, stream>>>(We1, att_edge1, We2, att_edge2, we1, we2);

    edge_pass_kernel<<<(E + 31) / 32, 256, 0, stream>>>((const float4*)eattr, eidx,
                                                        we1, we2, cnt, pack8, meta, E);
    scanA_kernel<<<nblkScan, 256, 0, stream>>>(cnt, bsum, n);
    scanB_kernel<<<1, 64, 0, stream>>>(bsum, boff, nblkScan);
    scanC_kernel<<<nblkScan, 256, 0, stream>>>(cnt, boff, row_ptr, n, E);

    scatter_kernel<<<(E + 255) / 256, 256, 0, stream>>>(pack8, meta, row_ptr, s_rec, E);

    int ngrid = (n + 3) / 4;
    // layer 1
    gemm_kernel<128><<<ngrid, 256, 0, stream>>>(x, W1, att_src1, att_dst1,
                                                bufA, a_src, a_dst, n);
    agg_fused_kernel<0, true><<<ngrid, 256, 0, stream>>>(row_ptr, s_rec, a_src,
                                                         a_dst, (const ushort4*)bufA,
                                                         b1, bufB, n);
    // layer 2
    gemm_kernel<64><<<ngrid, 256, 0, stream>>>(bufB, W2, att_src2, att_dst2,
                                               bufA, a_src, a_dst, n);
    agg_fused_kernel<1, false><<<ngrid, 256, 0, stream>>>(row_ptr, s_rec, a_src,
                                                          a_dst, (const ushort4*)bufA,
                                                          b2, out, n);
}

// Round 10
// 297.244 us; speedup vs baseline: 2.5468x; 1.0078x over previous
//
#include <hip/hip_runtime.h>
#include <hip/hip_bf16.h>

// bf16 round-to-nearest-even pack / unpack (bit ops)
__device__ __forceinline__ unsigned f2bf_rne(float f) {
    unsigned u = __float_as_uint(f);
    u += 0x7FFFu + ((u >> 16) & 1u);
    return u >> 16;
}
__device__ __forceinline__ float bf_lo(unsigned p) { return __uint_as_float(p << 16); }
__device__ __forceinline__ float bf_hi(unsigned p) { return __uint_as_float(p & 0xFFFF0000u); }
template <int I> __device__ __forceinline__ float bfsel(unsigned p) {
    return (I == 0) ? bf_lo(p) : bf_hi(p);
}

// ---------------------------------------------------------------------------
// init: zero cnt (all blocks) + we[k] = sum_c We[k][c]*att_edge[c] (block 0)
// ---------------------------------------------------------------------------
__global__ __launch_bounds__(256)
void init_kernel(int* __restrict__ cnt, int n,
                 const float* __restrict__ We1, const float* __restrict__ ae1v,
                 const float* __restrict__ We2, const float* __restrict__ ae2v,
                 float* __restrict__ we1, float* __restrict__ we2) {
    int i = blockIdx.x * 256 + threadIdx.x;
    if (i < n) cnt[i] = 0;
    if (blockIdx.x == 0 && threadIdx.x >= 64 && threadIdx.x < 128) {
        int t = threadIdx.x - 64;
        const float* W = (t < 32) ? We1 : We2;
        const float* a = (t < 32) ? ae1v : ae2v;
        float* o       = (t < 32) ? we1 : we2;
        int k = t & 31;
        float s = 0.f;
        for (int c = 0; c < 64; ++c) s += W[k * 64 + c] * a[c];
        o[k] = s;
    }
}

// ---------------------------------------------------------------------------
// streaming edge pass, 8 lanes per edge (coalesced 16B/lane):
// dot(ea, we) both layers + in-degree rank.
// pack8[e] = {src, bf16(ae1)|bf16(ae2)<<16};  meta[e] = rank<<16 | dst
// ---------------------------------------------------------------------------
__global__ __launch_bounds__(256)
void edge_pass_kernel(const float4* __restrict__ ea, const int* __restrict__ eidx,
                      const float* __restrict__ we1g, const float* __restrict__ we2g,
                      int* __restrict__ cnt, uint2* __restrict__ pack8,
                      unsigned* __restrict__ meta, int E) {
    int tid = threadIdx.x;
    int q = tid & 7;
    int e = blockIdx.x * 32 + (tid >> 3);
    if (e >= E) return;
    float4 w1 = ((const float4*)we1g)[q];
    float4 w2 = ((const float4*)we2g)[q];
    float4 v = ea[(size_t)e * 8 + q];
    float a1 = v.x * w1.x + v.y * w1.y + v.z * w1.z + v.w * w1.w;
    float a2 = v.x * w2.x + v.y * w2.y + v.z * w2.z + v.w * w2.w;
#pragma unroll
    for (int off = 1; off < 8; off <<= 1) {
        a1 += __shfl_xor(a1, off, 64);
        a2 += __shfl_xor(a2, off, 64);
    }
    if (q == 0) {
        int src = eidx[e];
        int dst = eidx[E + e];
        int rk = atomicAdd(&cnt[dst], 1);
        pack8[e] = make_uint2((unsigned)src, f2bf_rne(a1) | (f2bf_rne(a2) << 16));
        meta[e] = ((unsigned)rk << 16) | (unsigned)dst;
    }
}

// ---------------------------------------------------------------------------
// scan stage A: per-256-chunk sums
// ---------------------------------------------------------------------------
__global__ __launch_bounds__(256)
void scanA_kernel(const int* __restrict__ cnt, int* __restrict__ bsum, int n) {
    int idx = blockIdx.x * 256 + threadIdx.x;
    int v = (idx < n) ? cnt[idx] : 0;
#pragma unroll
    for (int off = 32; off >= 1; off >>= 1) v += __shfl_xor(v, off, 64);
    __shared__ int ws[4];
    int lane = threadIdx.x & 63, wid = threadIdx.x >> 6;
    if (lane == 0) ws[wid] = v;
    __syncthreads();
    if (threadIdx.x == 0) bsum[blockIdx.x] = ws[0] + ws[1] + ws[2] + ws[3];
}

// ---------------------------------------------------------------------------
// scan stage B: exclusive scan of chunk sums (single wave)
// ---------------------------------------------------------------------------
__global__ void scanB_kernel(const int* __restrict__ bsum, int* __restrict__ boff, int nb) {
    int lane = threadIdx.x;   // 64
    int carry = 0;
    for (int base = 0; base < nb; base += 64) {
        int idx = base + lane;
        int v = (idx < nb) ? bsum[idx] : 0;
        int s = v;
#pragma unroll
        for (int off = 1; off < 64; off <<= 1) {
            int t = __shfl_up(s, off, 64);
            if (lane >= off) s += t;
        }
        if (idx < nb) boff[idx] = carry + s - v;
        carry += __shfl(s, 63, 64);
    }
}

// ---------------------------------------------------------------------------
// scan stage C: in-chunk scan + chunk offset -> row_ptr
// ---------------------------------------------------------------------------
__global__ __launch_bounds__(256)
void scanC_kernel(const int* __restrict__ cnt, const int* __restrict__ boff,
                  int* __restrict__ row_ptr, int n, int E) {
    __shared__ int ws[4];
    __shared__ int woff[4];
    int idx = blockIdx.x * 256 + threadIdx.x;
    int lane = threadIdx.x & 63, wid = threadIdx.x >> 6;
    int v = (idx < n) ? cnt[idx] : 0;
    int s = v;
#pragma unroll
    for (int off = 1; off < 64; off <<= 1) {
        int t = __shfl_up(s, off, 64);
        if (lane >= off) s += t;
    }
    if (lane == 63) ws[wid] = s;
    __syncthreads();
    if (threadIdx.x == 0) {
        int run = 0;
        for (int w = 0; w < 4; ++w) { int t = ws[w]; woff[w] = run; run += t; }
    }
    __syncthreads();
    if (idx < n) row_ptr[idx] = boff[blockIdx.x] + woff[wid] + s - v;
    if (idx == 0) row_ptr[n] = E;
}

// ---------------------------------------------------------------------------
// scatter pass: sequential 12B read, single scattered 8B store.
// ---------------------------------------------------------------------------
__global__ __launch_bounds__(256)
void scatter_kernel(const uint2* __restrict__ pack8, const unsigned* __restrict__ meta,
                    const int* __restrict__ row_ptr, uint2* __restrict__ s_rec, int E) {
    int e = blockIdx.x * 256 + threadIdx.x;
    if (e >= E) return;
    unsigned m = meta[e];
    int dst = (int)(m & 0xFFFFu);
    int rk  = (int)(m >> 16);
    s_rec[row_ptr[dst] + rk] = pack8[e];
}

// ---------------------------------------------------------------------------
// H = X @ W + attn logit dots. W staged TRANSPOSED+PADDED in LDS so the
// inner loop is 1 ds_read_b128 per 4 FMAs (was 4x ds_read_b32).
// H stored bf16.
// ---------------------------------------------------------------------------
template <int INC>
__global__ __launch_bounds__(256)
void gemm_kernel(const float* __restrict__ X, const float* __restrict__ W,
                 const float* __restrict__ asv, const float* __restrict__ adv,
                 __hip_bfloat16* __restrict__ H, float* __restrict__ a_src,
                 float* __restrict__ a_dst, int n) {
    constexpr int LDW = INC + 4;                 // pad: bank-spread for b128
    __shared__ float Wl[64 * LDW];
    for (int t = threadIdx.x; t < INC * 64; t += 256) {
        int k = t >> 6, c = t & 63;
        Wl[c * LDW + k] = W[t];                  // transpose: Wl[c][k] = W[k][c]
    }
    __syncthreads();
    int wid = threadIdx.x >> 6, lane = threadIdx.x & 63;
    int i = blockIdx.x * 4 + wid;
    if (i >= n) return;
    const float4* xr = (const float4*)(X + (size_t)i * INC);
    const float4* wr = (const float4*)(Wl + lane * LDW);   // LDW%4==0 -> aligned
    float acc = 0.f;
#pragma unroll
    for (int k4 = 0; k4 < INC / 4; ++k4) {
        float4 xv = xr[k4];
        float4 wv = wr[k4];
        acc += xv.x * wv.x + xv.y * wv.y + xv.z * wv.z + xv.w * wv.w;
    }
    H[(size_t)i * 64 + lane] = __float2bfloat16(acc);
    float s = acc * asv[lane];
    float d = acc * adv[lane];
#pragma unroll
    for (int off = 32; off >= 1; off >>= 1) {
        s += __shfl_xor(s, off, 64);
        d += __shfl_xor(d, off, 64);
    }
    if (lane == 0) { a_src[i] = s; a_dst[i] = d; }
}

// bf16x4 (ushort4, 8B) -> 4 floats
__device__ __forceinline__ float4 bf4_to_f4(ushort4 u) {
    float4 f;
    f.x = __uint_as_float((unsigned)u.x << 16);
    f.y = __uint_as_float((unsigned)u.y << 16);
    f.z = __uint_as_float((unsigned)u.z << 16);
    f.w = __uint_as_float((unsigned)u.w << 16);
    return f;
}

// ---------------------------------------------------------------------------
// fused aggregation, SINGLE-PASS softmax (no max-subtract: logits bounded,
// f32 exp safe; softmax is shift-invariant). Weights -> wave-private LDS;
// gather: wave = 4 edge-slots x 16 channel-quads.
// ---------------------------------------------------------------------------
template <int AEIDX, bool RELU>
__global__ __launch_bounds__(256)
void agg_fused_kernel(const int* __restrict__ row_ptr, const uint2* __restrict__ s_rec,
                      const float* __restrict__ a_srcv, const float* __restrict__ a_dstv,
                      const ushort4* __restrict__ H4, const float* __restrict__ bias,
                      float* __restrict__ out, int n) {
    __shared__ uint2 wl[4][128];
    int wid = threadIdx.x >> 6, lane = threadIdx.x & 63;
    int i = blockIdx.x * 4 + wid;
    if (i >= n) return;
    int start = row_ptr[i], end = row_ptr[i + 1];
    int deg = end - start;
    float adst = a_dstv[i];

    // ---- phase 1: one pass -> w = exp(leakyrelu(logit)), den, ae-sum ----
    float w0 = 0.f, w1 = 0.f;
    int src0 = 0, src1 = 0;
    float aeloc = 0.f, dloc = 0.f;
    {
        int j = start + lane;
        if (j < end) {
            uint2 r = s_rec[j];
            float ae = bfsel<AEIDX>(r.y);
            src0 = (int)r.x;
            float a = a_srcv[src0] + adst + ae;
            a = a > 0.f ? a : 0.2f * a;
            w0 = __expf(a);
            aeloc += ae; dloc += w0;
        }
    }
    if (deg > 64) {
        int j = start + 64 + lane;
        if (j < end) {
            uint2 r = s_rec[j];
            float ae = bfsel<AEIDX>(r.y);
            src1 = (int)r.x;
            float a = a_srcv[src1] + adst + ae;
            a = a > 0.f ? a : 0.2f * a;
            w1 = __expf(a);
            aeloc += ae; dloc += w1;
        }
    }
    for (int base = start + 128; base < end; base += 64) {   // rare spill
        int j = base + lane;
        if (j < end) {
            uint2 r = s_rec[j];
            float ae = bfsel<AEIDX>(r.y);
            int s = (int)r.x;
            float a = a_srcv[s] + adst + ae;
            a = a > 0.f ? a : 0.2f * a;
            aeloc += ae; dloc += __expf(a);
        }
    }
#pragma unroll
    for (int off = 32; off >= 1; off >>= 1) {
        aeloc += __shfl_xor(aeloc, off, 64);
        dloc  += __shfl_xor(dloc, off, 64);
    }
    float ael = aeloc / (float)(deg > 0 ? deg : 1);
    float als = a_srcv[i] + adst + ael;
    als = als > 0.f ? als : 0.2f * als;
    float wself = __expf(als);
    float inv = 1.f / (dloc + wself + 1e-16f);

    // stage {src, w} in wave-private LDS (slots beyond deg carry w=0)
    wl[wid][lane]      = make_uint2((unsigned)src0, __float_as_uint(w0));
    wl[wid][64 + lane] = make_uint2((unsigned)src1, __float_as_uint(w1));

    // ---- phase 2: gather. wave = 4 edge-slots x 16 channel-quads ----
    int sub = lane >> 4;
    int c4  = lane & 15;
    float4 acc = make_float4(0.f, 0.f, 0.f, 0.f);
    int mainCnt = deg < 128 ? deg : 128;
#pragma unroll 4
    for (int r = 0; r < mainCnt; r += 4) {
        uint2 sw = wl[wid][r + sub];             // 8B LDS broadcast
        float w = __uint_as_float(sw.y);
        float4 hv = bf4_to_f4(H4[(size_t)((sw.x << 4) | (unsigned)c4)]);
        acc.x += w * hv.x; acc.y += w * hv.y;
        acc.z += w * hv.z; acc.w += w * hv.w;
    }
    for (int j = start + 128; j < end; j += 4) {   // rare spill: recompute w
        int jj = j + sub;
        if (jj < end) {
            uint2 r = s_rec[jj];
            float ae = bfsel<AEIDX>(r.y);
            int s = (int)r.x;
            float a = a_srcv[s] + adst + ae;
            a = a > 0.f ? a : 0.2f * a;
            float w = __expf(a);
            float4 hv = bf4_to_f4(H4[(size_t)(((unsigned)s << 4) | (unsigned)c4)]);
            acc.x += w * hv.x; acc.y += w * hv.y;
            acc.z += w * hv.z; acc.w += w * hv.w;
        }
    }
#pragma unroll
    for (int off = 16; off <= 32; off <<= 1) {
        acc.x += __shfl_xor(acc.x, off, 64);
        acc.y += __shfl_xor(acc.y, off, 64);
        acc.z += __shfl_xor(acc.z, off, 64);
        acc.w += __shfl_xor(acc.w, off, 64);
    }
    // self-loop + epilogue
    float4 hv = bf4_to_f4(H4[(size_t)(((unsigned)i << 4) | (unsigned)c4)]);
    float4 bv = ((const float4*)bias)[c4];
    float4 o;
    o.x = (acc.x + wself * hv.x) * inv + bv.x;
    o.y = (acc.y + wself * hv.y) * inv + bv.y;
    o.z = (acc.z + wself * hv.z) * inv + bv.z;
    o.w = (acc.w + wself * hv.w) * inv + bv.w;
    if (RELU) {
        o.x = fmaxf(o.x, 0.f); o.y = fmaxf(o.y, 0.f);
        o.z = fmaxf(o.z, 0.f); o.w = fmaxf(o.w, 0.f);
    }
    if (sub == 0) ((float4*)out)[(size_t)i * 16 + c4] = o;
}

// ---------------------------------------------------------------------------
extern "C" void kernel_launch(void* const* d_in, const int* in_sizes, int n_in,
                              void* d_out, int out_size, void* d_ws, size_t ws_size,
                              hipStream_t stream) {
    const float* x        = (const float*)d_in[0];
    const int*   eidx     = (const int*)d_in[1];
    const float* eattr    = (const float*)d_in[2];
    const float* W1       = (const float*)d_in[3];
    const float* We1      = (const float*)d_in[4];
    const float* att_src1 = (const float*)d_in[5];
    const float* att_dst1 = (const float*)d_in[6];
    const float* att_edge1= (const float*)d_in[7];
    const float* b1       = (const float*)d_in[8];
    const float* W2       = (const float*)d_in[9];
    const float* We2      = (const float*)d_in[10];
    const float* att_src2 = (const float*)d_in[11];
    const float* att_dst2 = (const float*)d_in[12];
    const float* att_edge2= (const float*)d_in[13];
    const float* b2       = (const float*)d_in[14];
    float* out = (float*)d_out;

    const int n = in_sizes[0] / 128;    // 50000
    const int E = in_sizes[1] / 2;      // 1600000

    char* ws = (char*)d_ws;
    size_t off = 0;
    auto carve = [&](size_t bytes) {
        char* p = ws + off;
        off = (off + bytes + 255) & ~(size_t)255;
        return p;
    };
    const int nblkScan = (n + 255) / 256;
    float*    we1    = (float*)carve(32 * 4);
    float*    we2    = (float*)carve(32 * 4);
    int*      cnt    = (int*)carve((size_t)n * 4);
    int*      bsum   = (int*)carve((size_t)nblkScan * 4);
    int*      boff   = (int*)carve((size_t)nblkScan * 4);
    int*      row_ptr= (int*)carve((size_t)(n + 1) * 4);
    uint2*    pack8  = (uint2*)carve((size_t)E * 8);
    unsigned* meta   = (unsigned*)carve((size_t)E * 4);
    uint2*    s_rec  = (uint2*)carve((size_t)E * 8);
    __hip_bfloat16* bufA = (__hip_bfloat16*)carve((size_t)n * 64 * 2);  // H bf16
    float*    bufB   = (float*)carve((size_t)n * 64 * 4);  // relu(gat1 out) f32
    float*    a_src  = (float*)carve((size_t)n * 4);
    float*    a_dst  = (float*)carve((size_t)n * 4);

    init_kernel<<<nblkScan, 256, 0, stream>>>(cnt, n, We1, att_edge1,
                                              We2, att_edge2, we1, we2);

    edge_pass_kernel<<<(E + 31) / 32, 256, 0, stream>>>((const float4*)eattr, eidx,
                                                        we1, we2, cnt, pack8, meta, E);
    scanA_kernel<<<nblkScan, 256, 0, stream>>>(cnt, bsum, n);
    scanB_kernel<<<1, 64, 0, stream>>>(bsum, boff, nblkScan);
    scanC_kernel<<<nblkScan, 256, 0, stream>>>(cnt, boff, row_ptr, n, E);

    scatter_kernel<<<(E + 255) / 256, 256, 0, stream>>>(pack8, meta, row_ptr, s_rec, E);

    int ngrid = (n + 3) / 4;
    // layer 1
    gemm_kernel<128><<<ngrid, 256, 0, stream>>>(x, W1, att_src1, att_dst1,
                                                bufA, a_src, a_dst, n);
    agg_fused_kernel<0, true><<<ngrid, 256, 0, stream>>>(row_ptr, s_rec, a_src,
                                                         a_dst, (const ushort4*)bufA,
                                                         b1, bufB, n);
    // layer 2
    gemm_kernel<64><<<ngrid, 256, 0, stream>>>(bufB, W2, att_src2, att_dst2,
                                               bufA, a_src, a_dst, n);
    agg_fused_kernel<1, false><<<ngrid, 256, 0, stream>>>(row_ptr, s_rec, a_src,
                                                          a_dst, (const ushort4*)bufA,
                                                          b2, out, n);
}